// Round 4
// baseline (5135.260 us; speedup 1.0000x reference)
//
#include <hip/hip_runtime.h>
#include <cmath>

#define DIM 768
#define DEPTH 8
#define HEADS 12
#define DH 64
#define DFF 2048
#define NTOK 16384   // B*T*S = 2*32*256
#define BB 2
#define TT 32
#define SS 256
#define LDQ 2304     // packed qkv row stride (3*768)

typedef __attribute__((ext_vector_type(8))) short short8;
typedef __attribute__((ext_vector_type(4))) float f32x4;

__device__ __forceinline__ float sigmoidf_(float x) { return 1.0f / (1.0f + __expf(-x)); }
__device__ __forceinline__ float geluf_(float x) {
  return 0.5f * x * (1.0f + erff(x * 0.70710678118654752f));
}
__device__ __forceinline__ unsigned short f2bf(float x) {
  union { float f; unsigned int u; } a; a.f = x;
  unsigned int r = a.u + 0x7fff + ((a.u >> 16) & 1);   // RNE
  return (unsigned short)(r >> 16);
}
__device__ __forceinline__ float bf2f(unsigned short h) {
  union { unsigned int u; float f; } a; a.u = ((unsigned int)h) << 16;
  return a.f;
}
__device__ __forceinline__ void load_lds16(const void* g, void* l) {
  __builtin_amdgcn_global_load_lds(
      (const __attribute__((address_space(1))) unsigned int*)g,
      (__attribute__((address_space(3))) unsigned int*)l, 16, 0, 0);
}
// softclamp+exp: p = exp(50*tanh(sv/50)) = 2^72.1347 * 2^(-144.2695/(e^{sv/25}+1))
__device__ __forceinline__ float softclamp_exp(float sv) {
  float a = exp2f(sv * 0.057707802f);
  float rc = __builtin_amdgcn_rcpf(a + 1.0f);
  return exp2f(fmaf(-144.26950408f, rc, 72.13475204f));
}

// ---------------- RMSNorm: one block per row of 768 ----------------
template<int BF>
__global__ __launch_bounds__(256) void rmsnorm_kernel(
    const float* __restrict__ x, const float* __restrict__ w, void* __restrict__ outp)
{
  int row = blockIdx.x;
  int tid = threadIdx.x;
  const float* xr = x + (size_t)row * DIM;
  float v0 = xr[tid], v1 = xr[tid + 256], v2 = xr[tid + 512];
  float ss = v0 * v0 + v1 * v1 + v2 * v2;
  #pragma unroll
  for (int off = 32; off; off >>= 1) ss += __shfl_xor(ss, off);
  __shared__ float sred[4];
  if ((tid & 63) == 0) sred[tid >> 6] = ss;
  __syncthreads();
  float tot = sred[0] + sred[1] + sred[2] + sred[3];
  float r = rsqrtf(tot * (1.0f / DIM) + 1e-6f);
  if (BF) {
    unsigned short* orow = (unsigned short*)outp + (size_t)row * DIM;
    orow[tid]       = f2bf(v0 * r * w[tid]);
    orow[tid + 256] = f2bf(v1 * r * w[tid + 256]);
    orow[tid + 512] = f2bf(v2 * r * w[tid + 512]);
  } else {
    float* orow = (float*)outp + (size_t)row * DIM;
    orow[tid]       = v0 * r * w[tid];
    orow[tid + 256] = v1 * r * w[tid + 256];
    orow[tid + 512] = v2 * r * w[tid + 512];
  }
}

// ---------------- weight convert+transpose: W[K][N] f32 -> WT[N][K] bf16 ----------------
__global__ __launch_bounds__(256) void w_to_bt(
    const float* __restrict__ W, unsigned short* __restrict__ WT, int K, int N)
{
  __shared__ float t[32][33];
  int n0 = blockIdx.x * 32, k0 = blockIdx.y * 32;
  int c = threadIdx.x & 31, r8 = threadIdx.x >> 5;
  #pragma unroll
  for (int rr = r8; rr < 32; rr += 8)
    t[rr][c] = W[(size_t)(k0 + rr) * N + n0 + c];
  __syncthreads();
  #pragma unroll
  for (int rn = r8; rn < 32; rn += 8)
    WT[(size_t)(n0 + rn) * K + k0 + c] = f2bf(t[c][rn]);
}

// ---------------- per-layer weight conversion, single dispatch ----------------
// regions: [0,1728) qkv (3x 24x24 tiles), [1728,2304) wo, [2304,5376) win
// (glu-interleaved: out row n' <- src col b*16+r (r<16) or 2048+b*16+r-16, b=n'>>5),
// [5376,6912) wout
__global__ __launch_bounds__(256) void w_convert_layer(
    const float* __restrict__ Wq, const float* __restrict__ Wk,
    const float* __restrict__ Wv, const float* __restrict__ Wo,
    const float* __restrict__ Win, const float* __restrict__ Wout,
    unsigned short* __restrict__ wqkvT, unsigned short* __restrict__ woT,
    unsigned short* __restrict__ winT, unsigned short* __restrict__ woutT)
{
  __shared__ float tle[32][33];
  int t = blockIdx.x;
  const float* W; unsigned short* WT; int K, N, n0, k0, glu = 0;
  if (t < 1728) {
    int rg = t / 576, tt = t - rg * 576;
    W = (rg == 0) ? Wq : (rg == 1) ? Wk : Wv;
    WT = wqkvT + (size_t)rg * 768 * 768;
    K = 768; N = 768; n0 = (tt % 24) * 32; k0 = (tt / 24) * 32;
  } else if (t < 2304) {
    int tt = t - 1728; W = Wo; WT = woT;
    K = 768; N = 768; n0 = (tt % 24) * 32; k0 = (tt / 24) * 32;
  } else if (t < 5376) {
    int tt = t - 2304; W = Win; WT = winT;
    K = 768; N = 4096; n0 = (tt % 128) * 32; k0 = (tt / 128) * 32; glu = 1;
  } else {
    int tt = t - 5376; W = Wout; WT = woutT;
    K = 2048; N = 768; n0 = (tt % 24) * 32; k0 = (tt / 24) * 32;
  }
  int c = threadIdx.x & 31, r8 = threadIdx.x >> 5;
  int col = n0 + c;
  int scol = col;
  if (glu) {
    int b = col >> 5, rr2 = col & 31;
    scol = (rr2 < 16) ? (b * 16 + rr2) : (2048 + b * 16 + rr2 - 16);
  }
  for (int rr = r8; rr < 32; rr += 8)
    tle[rr][c] = W[(size_t)(k0 + rr) * N + scol];
  __syncthreads();
  for (int rn = r8; rn < 32; rn += 8)
    WT[(size_t)(n0 + rn) * K + k0 + c] = f2bf(tle[c][rn]);
}

// ---------------- bf16 MFMA GEMM: 128x128 tile, BK=32 (m97 structure) ----------------
// A: MxK bf16 row-major. BT: NxK bf16 row-major (= B transposed).
// MODE 0: Cf = A@B (+bias)            (fp32 out)
// MODE 1: Cf += A@B (+bias)           (fp32 accumulate)
// MODE 2: Hg = bf16(A@B + bias)       (bf16 out)
// MODE 3: glu-interleaved B (16-col a/g blocks): Hg[M][N/2] = bf16(a * gelu(g))
template<int MODE>
__global__ __launch_bounds__(256) void gemm_bf16(
    const unsigned short* __restrict__ A, const unsigned short* __restrict__ BT,
    float* __restrict__ Cf, unsigned short* __restrict__ Hg,
    const float* __restrict__ bias, int M, int N, int K)
{
  __shared__ unsigned short As[128 * 32];
  __shared__ unsigned short Bs[128 * 32];
  const int tid = threadIdx.x;
  const int wave = tid >> 6;
  const int lane = tid & 63;
  const int bm = blockIdx.y * 128;
  const int bn = blockIdx.x * 128;
  const int wm = (wave & 1) * 64;
  const int wn = (wave >> 1) * 64;

  f32x4 acc[4][4];
  #pragma unroll
  for (int i = 0; i < 4; ++i)
    #pragma unroll
    for (int j = 0; j < 4; ++j) acc[i][j] = (f32x4){0.f, 0.f, 0.f, 0.f};

  const int srow = wave * 32 + (lane >> 2);
  const int skoff = (lane & 3) * 8;            // ushorts (16 B)
  const unsigned short* gA = A + (size_t)(bm + srow) * K + skoff;
  const unsigned short* gB = BT + (size_t)(bn + srow) * K + skoff;
  unsigned short* lA = &As[(wave * 32) * 32];
  unsigned short* lB = &Bs[(wave * 32) * 32];

  const int fr = lane & 15;
  const int fq = (lane >> 4) * 8;

  for (int k0 = 0; k0 < K; k0 += 32) {
    load_lds16(gA + k0, lA);
    load_lds16(gA + k0 + 16 * K, lA + 16 * 32);
    load_lds16(gB + k0, lB);
    load_lds16(gB + k0 + 16 * K, lB + 16 * 32);
    __syncthreads();
    short8 a[4], b[4];
    #pragma unroll
    for (int i = 0; i < 4; ++i)
      a[i] = *(const short8*)&As[(wm + 16 * i + fr) * 32 + fq];
    #pragma unroll
    for (int j = 0; j < 4; ++j)
      b[j] = *(const short8*)&Bs[(wn + 16 * j + fr) * 32 + fq];
    #pragma unroll
    for (int i = 0; i < 4; ++i)
      #pragma unroll
      for (int j = 0; j < 4; ++j)
        acc[i][j] = __builtin_amdgcn_mfma_f32_16x16x32_bf16(a[i], b[j], acc[i][j], 0, 0, 0);
    __syncthreads();
  }

  const int crow0 = bm + wm + (lane >> 4) * 4;
  const int ccol0 = bn + wn + fr;
  float bv[4];
  if (MODE != 3) {
    #pragma unroll
    for (int j = 0; j < 4; ++j) bv[j] = bias ? bias[ccol0 + 16 * j] : 0.0f;
  }
  #pragma unroll
  for (int i = 0; i < 4; ++i) {
    #pragma unroll
    for (int r = 0; r < 4; ++r) {
      int row = crow0 + 16 * i + r;
      if (MODE == 3) {
        #pragma unroll
        for (int pj = 0; pj < 2; ++pj) {
          int b32 = (bn + wn + 32 * pj) >> 5;
          float av = acc[i][2 * pj][r] + bias[b32 * 16 + fr];
          float gv = acc[i][2 * pj + 1][r] + bias[2048 + b32 * 16 + fr];
          Hg[(size_t)row * (N >> 1) + b32 * 16 + fr] = f2bf(av * geluf_(gv));
        }
      } else {
        #pragma unroll
        for (int j = 0; j < 4; ++j) {
          int col = ccol0 + 16 * j;
          size_t idx = (size_t)row * N + col;
          float val = acc[i][j][r] + bv[j];
          if (MODE == 0) Cf[idx] = val;
          else if (MODE == 1) Cf[idx] += val;
          else Hg[idx] = f2bf(val);
        }
      }
    }
  }
}

// ---------------- N=12 dual projection + sigmoid (mix & gate in one pass) ----------------
__global__ __launch_bounds__(256) void proj12x2_kernel(
    const unsigned short* __restrict__ A, const float* __restrict__ Bw1,
    const float* __restrict__ b1, const float* __restrict__ Bw2,
    float* __restrict__ out1, float* __restrict__ out2)
{
  int row = blockIdx.x * 4 + (threadIdx.x >> 6);
  int lane = threadIdx.x & 63;
  const unsigned short* ar = A + (size_t)row * DIM;
  float acc1[HEADS], acc2[HEADS];
  #pragma unroll
  for (int j = 0; j < HEADS; ++j) { acc1[j] = 0.0f; acc2[j] = 0.0f; }
  for (int k2 = lane; k2 < DIM; k2 += 64) {
    float a = bf2f(ar[k2]);
    const float* bw1 = Bw1 + (size_t)k2 * HEADS;
    const float* bw2 = Bw2 + (size_t)k2 * HEADS;
    #pragma unroll
    for (int j = 0; j < HEADS; ++j) {
      acc1[j] = fmaf(a, bw1[j], acc1[j]);
      acc2[j] = fmaf(a, bw2[j], acc2[j]);
    }
  }
  #pragma unroll
  for (int j = 0; j < HEADS; ++j) {
    #pragma unroll
    for (int off = 32; off; off >>= 1) {
      acc1[j] += __shfl_xor(acc1[j], off);
      acc2[j] += __shfl_xor(acc2[j], off);
    }
  }
  if (lane < HEADS) {
    out1[(size_t)row * HEADS + lane] = sigmoidf_(acc1[lane] + b1[lane]);
    out2[(size_t)row * HEADS + lane] = sigmoidf_(acc2[lane]);
  }
}

// ---------------- qkv postprocess (time layers only): v-lerp, k-norm+gamma, rotary ----------------
__global__ __launch_bounds__(768) void qkv_fix_kernel(
    unsigned short* __restrict__ qkv, const unsigned short* __restrict__ rvb,
    const float* __restrict__ mix, const float* __restrict__ kgam, int is_time)
{
  int tok = blockIdx.x;
  int h = threadIdx.x >> 6;
  int d = threadIdx.x & 63;
  size_t rowb = (size_t)tok * LDQ + h * DH + d;
  float kv = bf2f(qkv[rowb + 768]);
  float ss = kv * kv;
  #pragma unroll
  for (int off = 32; off; off >>= 1) ss += __shfl_xor(ss, off);
  float nrm = fmaxf(sqrtf(ss), 1e-12f);
  kv = kv / nrm * (kgam[h * DH + d] + 1.0f) * 8.0f;   // sqrt(DH)=8
  float mv = mix[(size_t)tok * HEADS + h];
  float vv = bf2f(qkv[rowb + 1536]);
  float rvv = bf2f(rvb[(size_t)tok * DIM + h * DH + d]);
  qkv[rowb + 1536] = f2bf(vv + mv * (rvv - vv));
  float qv = bf2f(qkv[rowb]);
  if (is_time) {
    int t = (tok >> 8) & 31;          // token = (b*32+t)*256+s
    int j = d & 31;
    float ang = (float)t * __expf(-(float)j * (9.210340371976184f / 32.0f));
    float cs = cosf(ang), sn = sinf(ang);
    float qp = __shfl_xor(qv, 32);
    float kp = __shfl_xor(kv, 32);
    float sgn = (d < 32) ? -1.0f : 1.0f;
    qv = qv * cs + sgn * qp * sn;
    kv = kv * cs + sgn * kp * sn;
  }
  qkv[rowb] = f2bf(qv);
  qkv[rowb + 768] = f2bf(kv);
}

// ---------------- MFMA space attention, qkv-fix fused into staging ----------------
// grid (BB*TT*2, HEADS): block = 128 q-rows of one (seq bp, head h); wave = 32 q-rows.
// K staged with l2norm*(gamma+1)*8 applied (8-lane group reduce per row);
// V staged with value-residual lerp applied.
__global__ __launch_bounds__(256, 3) void attn_mfma_kernel(
    const unsigned short* __restrict__ q, const unsigned short* __restrict__ k,
    const unsigned short* __restrict__ v, const unsigned short* __restrict__ rvb,
    const float* __restrict__ mix, const float* __restrict__ gate,
    const float* __restrict__ kgam, unsigned short* __restrict__ o)
{
  __shared__ __align__(16) unsigned short Ks[128 * 64];    // 16 KB, u^=row&7
  __shared__ __align__(16) unsigned short VsT[64 * 128];   // 16 KB, u^=d&15
  __shared__ __align__(16) unsigned short Pw[4][32 * 64];  // 16 KB, u^=row&7
  const int tid = threadIdx.x;
  const int wave = tid >> 6;
  const int lane = tid & 63;
  const int g = lane >> 4;
  const int c16 = lane & 15;
  const int bp = blockIdx.x >> 1;
  const int qh = blockIdx.x & 1;
  const int h = blockIdx.y;
  const size_t qoff = (size_t)bp * SS * LDQ + h * DH;
  const int qbase = qh * 128 + wave * 32;

  // Q fragments: wave owns rows [qbase, qbase+32)
  short8 aq[2][2];
  #pragma unroll
  for (int i = 0; i < 2; ++i) {
    const unsigned short* qp = q + qoff + (size_t)(qbase + i * 16 + c16) * LDQ;
    #pragma unroll
    for (int cc = 0; cc < 2; ++cc)
      aq[i][cc] = *(const short8*)(qp + cc * 32 + g * 8);
  }

  f32x4 oacc[2][4];
  float rs[2][4];
  #pragma unroll
  for (int i = 0; i < 2; ++i)
    #pragma unroll
    for (int j = 0; j < 4; ++j) {
      oacc[i][j] = (f32x4){0.f, 0.f, 0.f, 0.f};
      rs[i][j] = 0.f;
    }

  for (int half = 0; half < 2; ++half) {
    const int r0 = half * 128;
    // ---- stage K rows [r0,r0+128) with k-norm+gamma fused ----
    #pragma unroll
    for (int it = 0; it < 4; ++it) {
      int f = tid + it * 256;
      int row = f >> 3, u = f & 7;
      short8 t8 = *(const short8*)(k + qoff + (size_t)(r0 + row) * LDQ + u * 8);
      float kv[8];
      float ss = 0.f;
      #pragma unroll
      for (int c = 0; c < 8; ++c) { kv[c] = bf2f((unsigned short)t8[c]); ss += kv[c] * kv[c]; }
      ss += __shfl_xor(ss, 1); ss += __shfl_xor(ss, 2); ss += __shfl_xor(ss, 4);
      float inv = 8.0f / fmaxf(sqrtf(ss), 1e-12f);   // sqrt(DH)=8 folded in
      float4 kg0 = *(const float4*)(kgam + h * DH + u * 8);
      float4 kg1 = *(const float4*)(kgam + h * DH + u * 8 + 4);
      short8 o8;
      o8[0] = (short)f2bf(kv[0] * inv * (kg0.x + 1.0f));
      o8[1] = (short)f2bf(kv[1] * inv * (kg0.y + 1.0f));
      o8[2] = (short)f2bf(kv[2] * inv * (kg0.z + 1.0f));
      o8[3] = (short)f2bf(kv[3] * inv * (kg0.w + 1.0f));
      o8[4] = (short)f2bf(kv[4] * inv * (kg1.x + 1.0f));
      o8[5] = (short)f2bf(kv[5] * inv * (kg1.y + 1.0f));
      o8[6] = (short)f2bf(kv[6] * inv * (kg1.z + 1.0f));
      o8[7] = (short)f2bf(kv[7] * inv * (kg1.w + 1.0f));
      *(short8*)&Ks[row * 64 + ((u ^ (row & 7)) << 3)] = o8;
    }
    // ---- stage V transposed with value-residual lerp fused ----
    #pragma unroll
    for (int it = 0; it < 4; ++it) {
      int f = tid + it * 256;
      int j = f & 127, dq = f >> 7;
      int tok = bp * SS + r0 + j;
      short8 v8 = *(const short8*)(v + qoff + (size_t)(r0 + j) * LDQ + dq * 8);
      short8 r8 = *(const short8*)(rvb + (size_t)tok * DIM + h * DH + dq * 8);
      float mv = mix[(size_t)tok * HEADS + h];
      int u = j >> 3;
      #pragma unroll
      for (int c = 0; c < 8; ++c) {
        int d = dq * 8 + c;
        float vv = bf2f((unsigned short)v8[c]);
        float val = vv + mv * (bf2f((unsigned short)r8[c]) - vv);
        VsT[d * 128 + ((u ^ (d & 15)) << 3) + (j & 7)] = f2bf(val);
      }
    }
    __syncthreads();

    #pragma unroll
    for (int jc = 0; jc < 2; ++jc) {
      const int lr0 = jc * 64;
      // ---- S = Q K^T for 32 q-rows x 64 k-cols ----
      f32x4 s[2][4];
      #pragma unroll
      for (int i = 0; i < 2; ++i)
        #pragma unroll
        for (int j = 0; j < 4; ++j) s[i][j] = (f32x4){0.f, 0.f, 0.f, 0.f};
      #pragma unroll
      for (int jt = 0; jt < 4; ++jt) {
        int row = lr0 + jt * 16 + c16;
        short8 b0 = *(const short8*)&Ks[row * 64 + ((g ^ (row & 7)) << 3)];
        short8 b1 = *(const short8*)&Ks[row * 64 + (((4 + g) ^ (row & 7)) << 3)];
        #pragma unroll
        for (int i = 0; i < 2; ++i) {
          s[i][jt] = __builtin_amdgcn_mfma_f32_16x16x32_bf16(aq[i][0], b0, s[i][jt], 0, 0, 0);
          s[i][jt] = __builtin_amdgcn_mfma_f32_16x16x32_bf16(aq[i][1], b1, s[i][jt], 0, 0, 0);
        }
      }
      // ---- softclamp + exp; bf16 P to wave-private LDS ----
      #pragma unroll
      for (int i = 0; i < 2; ++i) {
        #pragma unroll
        for (int jt = 0; jt < 4; ++jt) {
          int pj = jt * 16 + c16;
          int uj = pj >> 3;
          #pragma unroll
          for (int r = 0; r < 4; ++r) {
            float p = softclamp_exp(s[i][jt][r] * 0.125f);
            unsigned short pb = f2bf(p);
            rs[i][r] += bf2f(pb);
            int prow = i * 16 + g * 4 + r;
            Pw[wave][prow * 64 + ((uj ^ (prow & 7)) << 3) + (pj & 7)] = pb;
          }
        }
      }
      // ---- O += P V ----
      #pragma unroll
      for (int jj = 0; jj < 2; ++jj) {
        short8 pa[2];
        #pragma unroll
        for (int i = 0; i < 2; ++i) {
          int prow = i * 16 + c16;
          int u = jj * 4 + g;
          pa[i] = *(const short8*)&Pw[wave][prow * 64 + ((u ^ (prow & 7)) << 3)];
        }
        const int jl = lr0 + jj * 32 + g * 8;
        const int uv = jl >> 3;
        #pragma unroll
        for (int dt = 0; dt < 4; ++dt) {
          int d = dt * 16 + c16;
          short8 bv = *(const short8*)&VsT[d * 128 + ((uv ^ (d & 15)) << 3)];
          #pragma unroll
          for (int i = 0; i < 2; ++i)
            oacc[i][dt] = __builtin_amdgcn_mfma_f32_16x16x32_bf16(pa[i], bv, oacc[i][dt], 0, 0, 0);
        }
      }
    }
    __syncthreads();
  }

  #pragma unroll
  for (int i = 0; i < 2; ++i)
    #pragma unroll
    for (int r = 0; r < 4; ++r) {
      float t = rs[i][r];
      t += __shfl_xor(t, 1); t += __shfl_xor(t, 2);
      t += __shfl_xor(t, 4); t += __shfl_xor(t, 8);
      rs[i][r] = t;
    }
  #pragma unroll
  for (int i = 0; i < 2; ++i) {
    #pragma unroll
    for (int r = 0; r < 4; ++r) {
      int row = qbase + i * 16 + g * 4 + r;
      int tq = bp * SS + row;
      float gt = gate[(size_t)tq * HEADS + h] / rs[i][r];
      unsigned short* op = o + (size_t)tq * DIM + h * DH;
      #pragma unroll
      for (int dt = 0; dt < 4; ++dt)
        op[dt * 16 + c16] = f2bf(oacc[i][dt][r] * gt);
    }
  }
}

// ---------------- MFMA time attention (bf16 in): wave = one (b,s) sequence ----------------
__global__ __launch_bounds__(256, 3) void attn_time_mfma(
    const unsigned short* __restrict__ q, const unsigned short* __restrict__ k,
    const unsigned short* __restrict__ v, const float* __restrict__ gate,
    unsigned short* __restrict__ o)
{
  __shared__ __align__(16) unsigned short VT[4][64 * 32];  // [d][t'], u^=d&3
  __shared__ __align__(16) unsigned short Pw[4][32 * 32];  // [t][t'], u^=t&3
  const int tid = threadIdx.x;
  const int wave = tid >> 6;
  const int lane = tid & 63;
  const int g = lane >> 4;
  const int c16 = lane & 15;
  const int h = blockIdx.y;
  const int sp = blockIdx.x * 4 + wave;                 // 0..511
  const int base = (sp >> 8) * (TT * SS) + (sp & 255);  // b*8192 + s

  short8 aq[2][2], bk[2][2];
  #pragma unroll
  for (int i = 0; i < 2; ++i) {
    const unsigned short* qp = q + (size_t)(base + (i * 16 + c16) * SS) * LDQ + h * DH;
    const unsigned short* kp = k + (size_t)(base + (i * 16 + c16) * SS) * LDQ + h * DH;
    #pragma unroll
    for (int cc = 0; cc < 2; ++cc) {
      aq[i][cc] = *(const short8*)(qp + cc * 32 + g * 8);
      bk[i][cc] = *(const short8*)(kp + cc * 32 + g * 8);
    }
  }

  // stage V transposed: lane handles t' = lane>>1, d-half = (lane&1)*32
  {
    int tp = lane >> 1;
    int dh0 = (lane & 1) * 32;
    const unsigned short* vp = v + (size_t)(base + tp * SS) * LDQ + h * DH + dh0;
    int ut = tp >> 3;
    #pragma unroll
    for (int j4 = 0; j4 < 4; ++j4) {
      short8 t = *(const short8*)(vp + j4 * 8);
      #pragma unroll
      for (int c = 0; c < 8; ++c) {
        int d = dh0 + j4 * 8 + c;
        VT[wave][d * 32 + ((ut ^ (d & 3)) << 3) + (tp & 7)] = (unsigned short)t[c];
      }
    }
  }

  // S = Q K^T (32x32)
  f32x4 s[2][2];
  #pragma unroll
  for (int i = 0; i < 2; ++i)
    #pragma unroll
    for (int j = 0; j < 2; ++j) s[i][j] = (f32x4){0.f, 0.f, 0.f, 0.f};
  #pragma unroll
  for (int jt = 0; jt < 2; ++jt)
    #pragma unroll
    for (int i = 0; i < 2; ++i) {
      s[i][jt] = __builtin_amdgcn_mfma_f32_16x16x32_bf16(aq[i][0], bk[jt][0], s[i][jt], 0, 0, 0);
      s[i][jt] = __builtin_amdgcn_mfma_f32_16x16x32_bf16(aq[i][1], bk[jt][1], s[i][jt], 0, 0, 0);
    }

  // softclamp + exp + causal mask; bf16 P to wave-private LDS
  float rs[2][4];
  #pragma unroll
  for (int i = 0; i < 2; ++i)
    #pragma unroll
    for (int r = 0; r < 4; ++r) rs[i][r] = 0.f;
  #pragma unroll
  for (int i = 0; i < 2; ++i) {
    #pragma unroll
    for (int jt = 0; jt < 2; ++jt) {
      int pj = jt * 16 + c16;
      int uj = pj >> 3;
      #pragma unroll
      for (int r = 0; r < 4; ++r) {
        int t = i * 16 + g * 4 + r;
        float p = softclamp_exp(s[i][jt][r] * 0.125f);
        unsigned short pb = (pj <= t) ? f2bf(p) : (unsigned short)0;
        rs[i][r] += bf2f(pb);
        Pw[wave][t * 32 + ((uj ^ (t & 3)) << 3) + (pj & 7)] = pb;
      }
    }
  }

  // O = P V
  short8 pa[2];
  #pragma unroll
  for (int i = 0; i < 2; ++i) {
    int prow = i * 16 + c16;
    pa[i] = *(const short8*)&Pw[wave][prow * 32 + ((g ^ (prow & 3)) << 3)];
  }
  f32x4 oacc[2][4];
  #pragma unroll
  for (int dt = 0; dt < 4; ++dt) {
    int d = dt * 16 + c16;
    short8 bv = *(const short8*)&VT[wave][d * 32 + ((g ^ (d & 3)) << 3)];
    #pragma unroll
    for (int i = 0; i < 2; ++i)
      oacc[i][dt] = __builtin_amdgcn_mfma_f32_16x16x32_bf16(
          pa[i], bv, (f32x4){0.f, 0.f, 0.f, 0.f}, 0, 0, 0);
  }

  #pragma unroll
  for (int i = 0; i < 2; ++i)
    #pragma unroll
    for (int r = 0; r < 4; ++r) {
      float t = rs[i][r];
      t += __shfl_xor(t, 1); t += __shfl_xor(t, 2);
      t += __shfl_xor(t, 4); t += __shfl_xor(t, 8);
      rs[i][r] = t;
    }
  #pragma unroll
  for (int i = 0; i < 2; ++i) {
    #pragma unroll
    for (int r = 0; r < 4; ++r) {
      int t = i * 16 + g * 4 + r;
      int tok = base + t * SS;
      float gt = gate[(size_t)tok * HEADS + h] / rs[i][r];
      unsigned short* op = o + (size_t)tok * DIM + h * DH;
      #pragma unroll
      for (int dt = 0; dt < 4; ++dt)
        op[dt * 16 + c16] = f2bf(oacc[i][dt][r] * gt);
    }
  }
}

// ---------------- driver ----------------
extern "C" void kernel_launch(void* const* d_in, const int* in_sizes, int n_in,
                              void* d_out, int out_size, void* d_ws, size_t ws_size,
                              hipStream_t stream)
{
  const float* tokens = (const float*)d_in[0];
  const float* attn_norm_w = (const float*)d_in[1];
  const float* Wq   = (const float*)d_in[2];
  const float* Wk   = (const float*)d_in[3];
  const float* Wv   = (const float*)d_in[4];
  const float* Wo   = (const float*)d_in[5];
  const float* Wg   = (const float*)d_in[6];
  const float* Wmix = (const float*)d_in[7];
  const float* bmix = (const float*)d_in[8];
  const float* kgam = (const float*)d_in[9];
  const float* ffw  = (const float*)d_in[10];
  const float* Win  = (const float*)d_in[11];
  const float* bin  = (const float*)d_in[12];
  const float* Wout = (const float*)d_in[13];
  const float* bout = (const float*)d_in[14];
  const float* vrw  = (const float*)d_in[15];
  const float* vrW  = (const float*)d_in[16];
  const float* fnw  = (const float*)d_in[17];

  const size_t NT = (size_t)NTOK * DIM;   // 12,582,912
  float* ws  = (float*)d_ws;
  float* x   = ws;                        // NT f32
  float* mix = x + NT;                    // NTOK*12
  float* gate = mix + (size_t)NTOK * HEADS;
  unsigned short* tn   = (unsigned short*)(gate + (size_t)NTOK * HEADS); // NT bf16
  unsigned short* qkv  = tn + NT;                        // NTOK*2304 bf16
  unsigned short* rvb  = qkv + (size_t)NTOK * LDQ;       // NT bf16
  unsigned short* wqkvT = rvb + NT;                      // 2304*768
  unsigned short* woT  = wqkvT + (size_t)2304 * 768;     // 768*768
  unsigned short* winT = woT + (size_t)768 * 768;        // 4096*768 (glu-interleaved)
  unsigned short* woutT= winT + (size_t)4096 * 768;      // 768*2048
  unsigned short* vrWT = woutT + (size_t)768 * 2048;     // 768*768
  unsigned short* hg   = qkv;   // FF hidden [NTOK][2048] aliases qkv

  hipMemcpyAsync(x, tokens, NT * sizeof(float), hipMemcpyDeviceToDevice, stream);

  // value residual: rvb = bf16(rmsnorm(tokens, vrw) @ vrW)
  w_to_bt<<<dim3(24, 24), 256, 0, stream>>>(vrW, vrWT, DIM, DIM);
  rmsnorm_kernel<1><<<NTOK, 256, 0, stream>>>(tokens, vrw, tn);
  gemm_bf16<2><<<dim3(6, 128), 256, 0, stream>>>(
      tn, vrWT, nullptr, rvb, nullptr, NTOK, DIM, DIM);

  for (int i = 0; i < DEPTH; ++i) {
    int is_time = ((i + 1) % 4 == 0) ? 1 : 0;
    // all per-layer weight conversion in one dispatch
    w_convert_layer<<<6912, 256, 0, stream>>>(
        Wq + (size_t)i * DIM * DIM, Wk + (size_t)i * DIM * DIM,
        Wv + (size_t)i * DIM * DIM, Wo + (size_t)i * DIM * DIM,
        Win + (size_t)i * DIM * 2 * DFF, Wout + (size_t)i * DFF * DIM,
        wqkvT, woT, winT, woutT);

    rmsnorm_kernel<1><<<NTOK, 256, 0, stream>>>(x, attn_norm_w + (size_t)i * DIM, tn);
    // fused qkv projection -> packed bf16 [tok][2304]
    gemm_bf16<2><<<dim3(18, 128), 256, 0, stream>>>(
        tn, wqkvT, nullptr, qkv, nullptr, NTOK, LDQ, DIM);
    proj12x2_kernel<<<NTOK / 4, 256, 0, stream>>>(
        tn, Wmix + (size_t)i * DIM * HEADS, bmix + (size_t)i * HEADS,
        Wg + (size_t)i * DIM * HEADS, mix, gate);
    if (is_time) {
      qkv_fix_kernel<<<dim3(NTOK), 768, 0, stream>>>(
          qkv, rvb, mix, kgam + (size_t)i * HEADS * DH, is_time);
      attn_time_mfma<<<dim3((BB * SS) / 4, HEADS), 256, 0, stream>>>(
          qkv, qkv + 768, qkv + 1536, gate, tn);
    } else {
      attn_mfma_kernel<<<dim3(BB * TT * 2, HEADS), 256, 0, stream>>>(
          qkv, qkv + 768, qkv + 1536, rvb, mix, gate,
          kgam + (size_t)i * HEADS * DH, tn);
    }
    gemm_bf16<1><<<dim3(6, 128), 256, 0, stream>>>(tn, woT, x, nullptr, nullptr, NTOK, DIM, DIM);
    // FF: rmsnorm -> glu-interleaved in-proj (MODE 3) -> out-proj
    rmsnorm_kernel<1><<<NTOK, 256, 0, stream>>>(x, ffw + (size_t)i * DIM, tn);
    gemm_bf16<3><<<dim3(32, 128), 256, 0, stream>>>(
        tn, winT, nullptr, hg, bin + (size_t)i * 2 * DFF, NTOK, 2 * DFF, DIM);
    gemm_bf16<1><<<dim3(6, 128), 256, 0, stream>>>(
        hg, woutT, x, nullptr, bout + (size_t)i * DIM, NTOK, DIM, DFF);
  }
  rmsnorm_kernel<0><<<NTOK, 256, 0, stream>>>(x, fnw, (float*)d_out);
}

// Round 6
// 4494.552 us; speedup vs baseline: 1.1426x; 1.1426x over previous
//
#include <hip/hip_runtime.h>
#include <cmath>

#define DIM 768
#define DEPTH 8
#define HEADS 12
#define DH 64
#define DFF 2048
#define NTOK 16384   // B*T*S = 2*32*256
#define BB 2
#define TT 32
#define SS 256
#define LDQ 2304     // packed qkv row stride (3*768)

typedef __attribute__((ext_vector_type(8))) short short8;
typedef __attribute__((ext_vector_type(4))) float f32x4;

__device__ __forceinline__ float sigmoidf_(float x) { return 1.0f / (1.0f + __expf(-x)); }
__device__ __forceinline__ float geluf_(float x) {
  return 0.5f * x * (1.0f + erff(x * 0.70710678118654752f));
}
__device__ __forceinline__ unsigned short f2bf(float x) {
  union { float f; unsigned int u; } a; a.f = x;
  unsigned int r = a.u + 0x7fff + ((a.u >> 16) & 1);   // RNE
  return (unsigned short)(r >> 16);
}
__device__ __forceinline__ float bf2f(unsigned short h) {
  union { unsigned int u; float f; } a; a.u = ((unsigned int)h) << 16;
  return a.f;
}
__device__ __forceinline__ void load_lds16(const void* g, void* l) {
  __builtin_amdgcn_global_load_lds(
      (const __attribute__((address_space(1))) unsigned int*)g,
      (__attribute__((address_space(3))) unsigned int*)l, 16, 0, 0);
}
// softclamp+exp: p = exp(50*tanh(sv/50)) = 2^72.1347 * 2^(-144.2695/(e^{sv/25}+1))
__device__ __forceinline__ float softclamp_exp(float sv) {
  float a = exp2f(sv * 0.057707802f);
  float rc = __builtin_amdgcn_rcpf(a + 1.0f);
  return exp2f(fmaf(-144.26950408f, rc, 72.13475204f));
}

// ---------------- RMSNorm: one block per row of 768 ----------------
template<int BF>
__global__ __launch_bounds__(256) void rmsnorm_kernel(
    const float* __restrict__ x, const float* __restrict__ w, void* __restrict__ outp)
{
  int row = blockIdx.x;
  int tid = threadIdx.x;
  const float* xr = x + (size_t)row * DIM;
  float v0 = xr[tid], v1 = xr[tid + 256], v2 = xr[tid + 512];
  float ss = v0 * v0 + v1 * v1 + v2 * v2;
  #pragma unroll
  for (int off = 32; off; off >>= 1) ss += __shfl_xor(ss, off);
  __shared__ float sred[4];
  if ((tid & 63) == 0) sred[tid >> 6] = ss;
  __syncthreads();
  float tot = sred[0] + sred[1] + sred[2] + sred[3];
  float r = rsqrtf(tot * (1.0f / DIM) + 1e-6f);
  if (BF) {
    unsigned short* orow = (unsigned short*)outp + (size_t)row * DIM;
    orow[tid]       = f2bf(v0 * r * w[tid]);
    orow[tid + 256] = f2bf(v1 * r * w[tid + 256]);
    orow[tid + 512] = f2bf(v2 * r * w[tid + 512]);
  } else {
    float* orow = (float*)outp + (size_t)row * DIM;
    orow[tid]       = v0 * r * w[tid];
    orow[tid + 256] = v1 * r * w[tid + 256];
    orow[tid + 512] = v2 * r * w[tid + 512];
  }
}

// ---------------- weight convert+transpose: W[K][N] f32 -> WT[N][K] bf16 ----------------
__global__ __launch_bounds__(256) void w_to_bt(
    const float* __restrict__ W, unsigned short* __restrict__ WT, int K, int N)
{
  __shared__ float t[32][33];
  int n0 = blockIdx.x * 32, k0 = blockIdx.y * 32;
  int c = threadIdx.x & 31, r8 = threadIdx.x >> 5;
  #pragma unroll
  for (int rr = r8; rr < 32; rr += 8)
    t[rr][c] = W[(size_t)(k0 + rr) * N + n0 + c];
  __syncthreads();
  #pragma unroll
  for (int rn = r8; rn < 32; rn += 8)
    WT[(size_t)(n0 + rn) * K + k0 + c] = f2bf(t[c][rn]);
}

// ---------------- per-layer weight conversion, single dispatch ----------------
// regions: [0,1728) qkv (3x 24x24 tiles), [1728,2304) wo, [2304,5376) win
// (glu-interleaved: out row n' <- src col b*16+r (r<16) or 2048+b*16+r-16, b=n'>>5),
// [5376,6912) wout
__global__ __launch_bounds__(256) void w_convert_layer(
    const float* __restrict__ Wq, const float* __restrict__ Wk,
    const float* __restrict__ Wv, const float* __restrict__ Wo,
    const float* __restrict__ Win, const float* __restrict__ Wout,
    unsigned short* __restrict__ wqkvT, unsigned short* __restrict__ woT,
    unsigned short* __restrict__ winT, unsigned short* __restrict__ woutT)
{
  __shared__ float tle[32][33];
  int t = blockIdx.x;
  const float* W; unsigned short* WT; int K, N, n0, k0, glu = 0;
  if (t < 1728) {
    int rg = t / 576, tt = t - rg * 576;
    W = (rg == 0) ? Wq : (rg == 1) ? Wk : Wv;
    WT = wqkvT + (size_t)rg * 768 * 768;
    K = 768; N = 768; n0 = (tt % 24) * 32; k0 = (tt / 24) * 32;
  } else if (t < 2304) {
    int tt = t - 1728; W = Wo; WT = woT;
    K = 768; N = 768; n0 = (tt % 24) * 32; k0 = (tt / 24) * 32;
  } else if (t < 5376) {
    int tt = t - 2304; W = Win; WT = winT;
    K = 768; N = 4096; n0 = (tt % 128) * 32; k0 = (tt / 128) * 32; glu = 1;
  } else {
    int tt = t - 5376; W = Wout; WT = woutT;
    K = 2048; N = 768; n0 = (tt % 24) * 32; k0 = (tt / 24) * 32;
  }
  int c = threadIdx.x & 31, r8 = threadIdx.x >> 5;
  int col = n0 + c;
  int scol = col;
  if (glu) {
    int b = col >> 5, rr2 = col & 31;
    scol = (rr2 < 16) ? (b * 16 + rr2) : (2048 + b * 16 + rr2 - 16);
  }
  for (int rr = r8; rr < 32; rr += 8)
    tle[rr][c] = W[(size_t)(k0 + rr) * N + scol];
  __syncthreads();
  for (int rn = r8; rn < 32; rn += 8)
    WT[(size_t)(n0 + rn) * K + k0 + c] = f2bf(tle[c][rn]);
}

// ---------------- bf16 MFMA GEMM: 128x128 tile, BK=32 (m97 structure) ----------------
// A: MxK bf16 row-major. BT: NxK bf16 row-major (= B transposed).
// MODE 0: Cf = A@B (+bias)            (fp32 out)
// MODE 1: Cf += A@B (+bias)           (fp32 accumulate)
// MODE 2: Hg = bf16(A@B + bias)       (bf16 out)
// MODE 3: glu-interleaved B (16-col a/g blocks): Hg[M][N/2] = bf16(a * gelu(g))
template<int MODE>
__global__ __launch_bounds__(256) void gemm_bf16(
    const unsigned short* __restrict__ A, const unsigned short* __restrict__ BT,
    float* __restrict__ Cf, unsigned short* __restrict__ Hg,
    const float* __restrict__ bias, int M, int N, int K)
{
  __shared__ unsigned short As[128 * 32];
  __shared__ unsigned short Bs[128 * 32];
  const int tid = threadIdx.x;
  const int wave = tid >> 6;
  const int lane = tid & 63;
  const int bm = blockIdx.y * 128;
  const int bn = blockIdx.x * 128;
  const int wm = (wave & 1) * 64;
  const int wn = (wave >> 1) * 64;

  f32x4 acc[4][4];
  #pragma unroll
  for (int i = 0; i < 4; ++i)
    #pragma unroll
    for (int j = 0; j < 4; ++j) acc[i][j] = (f32x4){0.f, 0.f, 0.f, 0.f};

  const int srow = wave * 32 + (lane >> 2);
  const int skoff = (lane & 3) * 8;            // ushorts (16 B)
  const unsigned short* gA = A + (size_t)(bm + srow) * K + skoff;
  const unsigned short* gB = BT + (size_t)(bn + srow) * K + skoff;
  unsigned short* lA = &As[(wave * 32) * 32];
  unsigned short* lB = &Bs[(wave * 32) * 32];

  const int fr = lane & 15;
  const int fq = (lane >> 4) * 8;

  for (int k0 = 0; k0 < K; k0 += 32) {
    load_lds16(gA + k0, lA);
    load_lds16(gA + k0 + 16 * K, lA + 16 * 32);
    load_lds16(gB + k0, lB);
    load_lds16(gB + k0 + 16 * K, lB + 16 * 32);
    __syncthreads();
    short8 a[4], b[4];
    #pragma unroll
    for (int i = 0; i < 4; ++i)
      a[i] = *(const short8*)&As[(wm + 16 * i + fr) * 32 + fq];
    #pragma unroll
    for (int j = 0; j < 4; ++j)
      b[j] = *(const short8*)&Bs[(wn + 16 * j + fr) * 32 + fq];
    #pragma unroll
    for (int i = 0; i < 4; ++i)
      #pragma unroll
      for (int j = 0; j < 4; ++j)
        acc[i][j] = __builtin_amdgcn_mfma_f32_16x16x32_bf16(a[i], b[j], acc[i][j], 0, 0, 0);
    __syncthreads();
  }

  const int crow0 = bm + wm + (lane >> 4) * 4;
  const int ccol0 = bn + wn + fr;
  float bv[4];
  if (MODE != 3) {
    #pragma unroll
    for (int j = 0; j < 4; ++j) bv[j] = bias ? bias[ccol0 + 16 * j] : 0.0f;
  }
  #pragma unroll
  for (int i = 0; i < 4; ++i) {
    #pragma unroll
    for (int r = 0; r < 4; ++r) {
      int row = crow0 + 16 * i + r;
      if (MODE == 3) {
        #pragma unroll
        for (int pj = 0; pj < 2; ++pj) {
          int b32 = (bn + wn + 32 * pj) >> 5;
          float av = acc[i][2 * pj][r] + bias[b32 * 16 + fr];
          float gv = acc[i][2 * pj + 1][r] + bias[2048 + b32 * 16 + fr];
          Hg[(size_t)row * (N >> 1) + b32 * 16 + fr] = f2bf(av * geluf_(gv));
        }
      } else {
        #pragma unroll
        for (int j = 0; j < 4; ++j) {
          int col = ccol0 + 16 * j;
          size_t idx = (size_t)row * N + col;
          float val = acc[i][j][r] + bv[j];
          if (MODE == 0) Cf[idx] = val;
          else if (MODE == 1) Cf[idx] += val;
          else Hg[idx] = f2bf(val);
        }
      }
    }
  }
}

// ---------------- N=12 dual projection + sigmoid (mix & gate in one pass) ----------------
__global__ __launch_bounds__(256) void proj12x2_kernel(
    const unsigned short* __restrict__ A, const float* __restrict__ Bw1,
    const float* __restrict__ b1, const float* __restrict__ Bw2,
    float* __restrict__ out1, float* __restrict__ out2)
{
  int row = blockIdx.x * 4 + (threadIdx.x >> 6);
  int lane = threadIdx.x & 63;
  const unsigned short* ar = A + (size_t)row * DIM;
  float acc1[HEADS], acc2[HEADS];
  #pragma unroll
  for (int j = 0; j < HEADS; ++j) { acc1[j] = 0.0f; acc2[j] = 0.0f; }
  for (int k2 = lane; k2 < DIM; k2 += 64) {
    float a = bf2f(ar[k2]);
    const float* bw1 = Bw1 + (size_t)k2 * HEADS;
    const float* bw2 = Bw2 + (size_t)k2 * HEADS;
    #pragma unroll
    for (int j = 0; j < HEADS; ++j) {
      acc1[j] = fmaf(a, bw1[j], acc1[j]);
      acc2[j] = fmaf(a, bw2[j], acc2[j]);
    }
  }
  #pragma unroll
  for (int j = 0; j < HEADS; ++j) {
    #pragma unroll
    for (int off = 32; off; off >>= 1) {
      acc1[j] += __shfl_xor(acc1[j], off);
      acc2[j] += __shfl_xor(acc2[j], off);
    }
  }
  if (lane < HEADS) {
    out1[(size_t)row * HEADS + lane] = sigmoidf_(acc1[lane] + b1[lane]);
    out2[(size_t)row * HEADS + lane] = sigmoidf_(acc2[lane]);
  }
}

// ---------------- qkv postprocess (time layers only): v-lerp, k-norm+gamma, rotary ----------------
__global__ __launch_bounds__(768) void qkv_fix_kernel(
    unsigned short* __restrict__ qkv, const unsigned short* __restrict__ rvb,
    const float* __restrict__ mix, const float* __restrict__ kgam, int is_time)
{
  int tok = blockIdx.x;
  int h = threadIdx.x >> 6;
  int d = threadIdx.x & 63;
  size_t rowb = (size_t)tok * LDQ + h * DH + d;
  float kv = bf2f(qkv[rowb + 768]);
  float ss = kv * kv;
  #pragma unroll
  for (int off = 32; off; off >>= 1) ss += __shfl_xor(ss, off);
  float nrm = fmaxf(sqrtf(ss), 1e-12f);
  kv = kv / nrm * (kgam[h * DH + d] + 1.0f) * 8.0f;   // sqrt(DH)=8
  float mv = mix[(size_t)tok * HEADS + h];
  float vv = bf2f(qkv[rowb + 1536]);
  float rvv = bf2f(rvb[(size_t)tok * DIM + h * DH + d]);
  qkv[rowb + 1536] = f2bf(vv + mv * (rvv - vv));
  float qv = bf2f(qkv[rowb]);
  if (is_time) {
    int t = (tok >> 8) & 31;          // token = (b*32+t)*256+s
    int j = d & 31;
    float ang = (float)t * __expf(-(float)j * (9.210340371976184f / 32.0f));
    float cs = cosf(ang), sn = sinf(ang);
    float qp = __shfl_xor(qv, 32);
    float kp = __shfl_xor(kv, 32);
    float sgn = (d < 32) ? -1.0f : 1.0f;
    qv = qv * cs + sgn * qp * sn;
    kv = kv * cs + sgn * kp * sn;
  }
  qkv[rowb] = f2bf(qv);
  qkv[rowb + 768] = f2bf(kv);
}

// ---------------- MFMA space attention, qkv-fix fused into staging ----------------
// grid (BB*TT*2, HEADS): block = 128 q-rows of one (seq bp, head h); wave = 32 q-rows.
// K staged with l2norm*(gamma+1)*8 applied; V staged with value-residual lerp.
// launch_bounds(256,2): cap 256 VGPR — the (256,3) cap of 170 forced scratch spill
// (rounds 2-4: WRITE_SIZE 249MB vs 25MB output). S computed in 32-col sub-chunks
// to keep peak pressure ~16 regs lower.
__global__ __launch_bounds__(256, 2) void attn_mfma_kernel(
    const unsigned short* __restrict__ q, const unsigned short* __restrict__ k,
    const unsigned short* __restrict__ v, const unsigned short* __restrict__ rvb,
    const float* __restrict__ mix, const float* __restrict__ gate,
    const float* __restrict__ kgam, unsigned short* __restrict__ o)
{
  __shared__ __align__(16) unsigned short Ks[128 * 64];    // 16 KB, u^=row&7
  __shared__ __align__(16) unsigned short VsT[64 * 128];   // 16 KB, u^=d&15
  __shared__ __align__(16) unsigned short Pw[4][32 * 64];  // 16 KB, u^=row&7
  const int tid = threadIdx.x;
  const int wave = tid >> 6;
  const int lane = tid & 63;
  const int g = lane >> 4;
  const int c16 = lane & 15;
  const int bp = blockIdx.x >> 1;
  const int qh = blockIdx.x & 1;
  const int h = blockIdx.y;
  const size_t qoff = (size_t)bp * SS * LDQ + h * DH;
  const int qbase = qh * 128 + wave * 32;

  // Q fragments: wave owns rows [qbase, qbase+32)
  short8 aq[2][2];
  #pragma unroll
  for (int i = 0; i < 2; ++i) {
    const unsigned short* qp = q + qoff + (size_t)(qbase + i * 16 + c16) * LDQ;
    #pragma unroll
    for (int cc = 0; cc < 2; ++cc)
      aq[i][cc] = *(const short8*)(qp + cc * 32 + g * 8);
  }

  f32x4 oacc[2][4];
  float rs[2][4];
  #pragma unroll
  for (int i = 0; i < 2; ++i)
    #pragma unroll
    for (int j = 0; j < 4; ++j) {
      oacc[i][j] = (f32x4){0.f, 0.f, 0.f, 0.f};
      rs[i][j] = 0.f;
    }

  for (int half = 0; half < 2; ++half) {
    const int r0 = half * 128;
    // ---- stage K rows [r0,r0+128) with k-norm+gamma fused ----
    #pragma unroll
    for (int it = 0; it < 4; ++it) {
      int f = tid + it * 256;
      int row = f >> 3, u = f & 7;
      short8 t8 = *(const short8*)(k + qoff + (size_t)(r0 + row) * LDQ + u * 8);
      float kv[8];
      float ss = 0.f;
      #pragma unroll
      for (int c = 0; c < 8; ++c) { kv[c] = bf2f((unsigned short)t8[c]); ss += kv[c] * kv[c]; }
      ss += __shfl_xor(ss, 1); ss += __shfl_xor(ss, 2); ss += __shfl_xor(ss, 4);
      float inv = 8.0f / fmaxf(sqrtf(ss), 1e-12f);   // sqrt(DH)=8 folded in
      float4 kg0 = *(const float4*)(kgam + h * DH + u * 8);
      float4 kg1 = *(const float4*)(kgam + h * DH + u * 8 + 4);
      short8 o8;
      o8[0] = (short)f2bf(kv[0] * inv * (kg0.x + 1.0f));
      o8[1] = (short)f2bf(kv[1] * inv * (kg0.y + 1.0f));
      o8[2] = (short)f2bf(kv[2] * inv * (kg0.z + 1.0f));
      o8[3] = (short)f2bf(kv[3] * inv * (kg0.w + 1.0f));
      o8[4] = (short)f2bf(kv[4] * inv * (kg1.x + 1.0f));
      o8[5] = (short)f2bf(kv[5] * inv * (kg1.y + 1.0f));
      o8[6] = (short)f2bf(kv[6] * inv * (kg1.z + 1.0f));
      o8[7] = (short)f2bf(kv[7] * inv * (kg1.w + 1.0f));
      *(short8*)&Ks[row * 64 + ((u ^ (row & 7)) << 3)] = o8;
    }
    // ---- stage V transposed with value-residual lerp fused ----
    #pragma unroll
    for (int it = 0; it < 4; ++it) {
      int f = tid + it * 256;
      int j = f & 127, dq = f >> 7;
      int tok = bp * SS + r0 + j;
      short8 v8 = *(const short8*)(v + qoff + (size_t)(r0 + j) * LDQ + dq * 8);
      short8 r8 = *(const short8*)(rvb + (size_t)tok * DIM + h * DH + dq * 8);
      float mv = mix[(size_t)tok * HEADS + h];
      int u = j >> 3;
      #pragma unroll
      for (int c = 0; c < 8; ++c) {
        int d = dq * 8 + c;
        float vv = bf2f((unsigned short)v8[c]);
        float val = vv + mv * (bf2f((unsigned short)r8[c]) - vv);
        VsT[d * 128 + ((u ^ (d & 15)) << 3) + (j & 7)] = f2bf(val);
      }
    }
    __syncthreads();

    #pragma unroll
    for (int jc = 0; jc < 2; ++jc) {
      const int lr0 = jc * 64;
      // ---- S = Q K^T + softmax, 32-col sub-chunks (low register pressure) ----
      #pragma unroll
      for (int jh = 0; jh < 2; ++jh) {
        f32x4 s[2][2];
        #pragma unroll
        for (int i = 0; i < 2; ++i)
          #pragma unroll
          for (int j = 0; j < 2; ++j) s[i][j] = (f32x4){0.f, 0.f, 0.f, 0.f};
        #pragma unroll
        for (int j2 = 0; j2 < 2; ++j2) {
          int jt = jh * 2 + j2;
          int row = lr0 + jt * 16 + c16;
          short8 b0 = *(const short8*)&Ks[row * 64 + ((g ^ (row & 7)) << 3)];
          short8 b1 = *(const short8*)&Ks[row * 64 + (((4 + g) ^ (row & 7)) << 3)];
          #pragma unroll
          for (int i = 0; i < 2; ++i) {
            s[i][j2] = __builtin_amdgcn_mfma_f32_16x16x32_bf16(aq[i][0], b0, s[i][j2], 0, 0, 0);
            s[i][j2] = __builtin_amdgcn_mfma_f32_16x16x32_bf16(aq[i][1], b1, s[i][j2], 0, 0, 0);
          }
        }
        #pragma unroll
        for (int i = 0; i < 2; ++i) {
          #pragma unroll
          for (int j2 = 0; j2 < 2; ++j2) {
            int pj = (jh * 2 + j2) * 16 + c16;
            int uj = pj >> 3;
            #pragma unroll
            for (int r = 0; r < 4; ++r) {
              float p = softclamp_exp(s[i][j2][r] * 0.125f);
              unsigned short pb = f2bf(p);
              rs[i][r] += bf2f(pb);
              int prow = i * 16 + g * 4 + r;
              Pw[wave][prow * 64 + ((uj ^ (prow & 7)) << 3) + (pj & 7)] = pb;
            }
          }
        }
      }
      // ---- O += P V ----
      #pragma unroll
      for (int jj = 0; jj < 2; ++jj) {
        short8 pa[2];
        #pragma unroll
        for (int i = 0; i < 2; ++i) {
          int prow = i * 16 + c16;
          int u = jj * 4 + g;
          pa[i] = *(const short8*)&Pw[wave][prow * 64 + ((u ^ (prow & 7)) << 3)];
        }
        const int jl = lr0 + jj * 32 + g * 8;
        const int uv = jl >> 3;
        #pragma unroll
        for (int dt = 0; dt < 4; ++dt) {
          int d = dt * 16 + c16;
          short8 bv = *(const short8*)&VsT[d * 128 + ((uv ^ (d & 15)) << 3)];
          #pragma unroll
          for (int i = 0; i < 2; ++i)
            oacc[i][dt] = __builtin_amdgcn_mfma_f32_16x16x32_bf16(pa[i], bv, oacc[i][dt], 0, 0, 0);
        }
      }
    }
    __syncthreads();
  }

  #pragma unroll
  for (int i = 0; i < 2; ++i)
    #pragma unroll
    for (int r = 0; r < 4; ++r) {
      float t = rs[i][r];
      t += __shfl_xor(t, 1); t += __shfl_xor(t, 2);
      t += __shfl_xor(t, 4); t += __shfl_xor(t, 8);
      rs[i][r] = t;
    }
  #pragma unroll
  for (int i = 0; i < 2; ++i) {
    #pragma unroll
    for (int r = 0; r < 4; ++r) {
      int row = qbase + i * 16 + g * 4 + r;
      int tq = bp * SS + row;
      float gt = gate[(size_t)tq * HEADS + h] / rs[i][r];
      unsigned short* op = o + (size_t)tq * DIM + h * DH;
      #pragma unroll
      for (int dt = 0; dt < 4; ++dt)
        op[dt * 16 + c16] = f2bf(oacc[i][dt][r] * gt);
    }
  }
}

// ---------------- MFMA time attention (bf16 in): wave = one (b,s) sequence ----------------
__global__ __launch_bounds__(256, 2) void attn_time_mfma(
    const unsigned short* __restrict__ q, const unsigned short* __restrict__ k,
    const unsigned short* __restrict__ v, const float* __restrict__ gate,
    unsigned short* __restrict__ o)
{
  __shared__ __align__(16) unsigned short VT[4][64 * 32];  // [d][t'], u^=d&3
  __shared__ __align__(16) unsigned short Pw[4][32 * 32];  // [t][t'], u^=t&3
  const int tid = threadIdx.x;
  const int wave = tid >> 6;
  const int lane = tid & 63;
  const int g = lane >> 4;
  const int c16 = lane & 15;
  const int h = blockIdx.y;
  const int sp = blockIdx.x * 4 + wave;                 // 0..511
  const int base = (sp >> 8) * (TT * SS) + (sp & 255);  // b*8192 + s

  short8 aq[2][2], bk[2][2];
  #pragma unroll
  for (int i = 0; i < 2; ++i) {
    const unsigned short* qp = q + (size_t)(base + (i * 16 + c16) * SS) * LDQ + h * DH;
    const unsigned short* kp = k + (size_t)(base + (i * 16 + c16) * SS) * LDQ + h * DH;
    #pragma unroll
    for (int cc = 0; cc < 2; ++cc) {
      aq[i][cc] = *(const short8*)(qp + cc * 32 + g * 8);
      bk[i][cc] = *(const short8*)(kp + cc * 32 + g * 8);
    }
  }

  // stage V transposed: lane handles t' = lane>>1, d-half = (lane&1)*32
  {
    int tp = lane >> 1;
    int dh0 = (lane & 1) * 32;
    const unsigned short* vp = v + (size_t)(base + tp * SS) * LDQ + h * DH + dh0;
    int ut = tp >> 3;
    #pragma unroll
    for (int j4 = 0; j4 < 4; ++j4) {
      short8 t = *(const short8*)(vp + j4 * 8);
      #pragma unroll
      for (int c = 0; c < 8; ++c) {
        int d = dh0 + j4 * 8 + c;
        VT[wave][d * 32 + ((ut ^ (d & 3)) << 3) + (tp & 7)] = (unsigned short)t[c];
      }
    }
  }

  // S = Q K^T (32x32)
  f32x4 s[2][2];
  #pragma unroll
  for (int i = 0; i < 2; ++i)
    #pragma unroll
    for (int j = 0; j < 2; ++j) s[i][j] = (f32x4){0.f, 0.f, 0.f, 0.f};
  #pragma unroll
  for (int jt = 0; jt < 2; ++jt)
    #pragma unroll
    for (int i = 0; i < 2; ++i) {
      s[i][jt] = __builtin_amdgcn_mfma_f32_16x16x32_bf16(aq[i][0], bk[jt][0], s[i][jt], 0, 0, 0);
      s[i][jt] = __builtin_amdgcn_mfma_f32_16x16x32_bf16(aq[i][1], bk[jt][1], s[i][jt], 0, 0, 0);
    }

  // softclamp + exp + causal mask; bf16 P to wave-private LDS
  float rs[2][4];
  #pragma unroll
  for (int i = 0; i < 2; ++i)
    #pragma unroll
    for (int r = 0; r < 4; ++r) rs[i][r] = 0.f;
  #pragma unroll
  for (int i = 0; i < 2; ++i) {
    #pragma unroll
    for (int jt = 0; jt < 2; ++jt) {
      int pj = jt * 16 + c16;
      int uj = pj >> 3;
      #pragma unroll
      for (int r = 0; r < 4; ++r) {
        int t = i * 16 + g * 4 + r;
        float p = softclamp_exp(s[i][jt][r] * 0.125f);
        unsigned short pb = (pj <= t) ? f2bf(p) : (unsigned short)0;
        rs[i][r] += bf2f(pb);
        Pw[wave][t * 32 + ((uj ^ (t & 3)) << 3) + (pj & 7)] = pb;
      }
    }
  }

  // O = P V
  short8 pa[2];
  #pragma unroll
  for (int i = 0; i < 2; ++i) {
    int prow = i * 16 + c16;
    pa[i] = *(const short8*)&Pw[wave][prow * 32 + ((g ^ (prow & 3)) << 3)];
  }
  f32x4 oacc[2][4];
  #pragma unroll
  for (int dt = 0; dt < 4; ++dt) {
    int d = dt * 16 + c16;
    short8 bv = *(const short8*)&VT[wave][d * 32 + ((g ^ (d & 3)) << 3)];
    #pragma unroll
    for (int i = 0; i < 2; ++i)
      oacc[i][dt] = __builtin_amdgcn_mfma_f32_16x16x32_bf16(
          pa[i], bv, (f32x4){0.f, 0.f, 0.f, 0.f}, 0, 0, 0);
  }

  #pragma unroll
  for (int i = 0; i < 2; ++i)
    #pragma unroll
    for (int r = 0; r < 4; ++r) {
      float t = rs[i][r];
      t += __shfl_xor(t, 1); t += __shfl_xor(t, 2);
      t += __shfl_xor(t, 4); t += __shfl_xor(t, 8);
      rs[i][r] = t;
    }
  #pragma unroll
  for (int i = 0; i < 2; ++i) {
    #pragma unroll
    for (int r = 0; r < 4; ++r) {
      int t = i * 16 + g * 4 + r;
      int tok = base + t * SS;
      float gt = gate[(size_t)tok * HEADS + h] / rs[i][r];
      unsigned short* op = o + (size_t)tok * DIM + h * DH;
      #pragma unroll
      for (int dt = 0; dt < 4; ++dt)
        op[dt * 16 + c16] = f2bf(oacc[i][dt][r] * gt);
    }
  }
}

// ---------------- driver ----------------
extern "C" void kernel_launch(void* const* d_in, const int* in_sizes, int n_in,
                              void* d_out, int out_size, void* d_ws, size_t ws_size,
                              hipStream_t stream)
{
  const float* tokens = (const float*)d_in[0];
  const float* attn_norm_w = (const float*)d_in[1];
  const float* Wq   = (const float*)d_in[2];
  const float* Wk   = (const float*)d_in[3];
  const float* Wv   = (const float*)d_in[4];
  const float* Wo   = (const float*)d_in[5];
  const float* Wg   = (const float*)d_in[6];
  const float* Wmix = (const float*)d_in[7];
  const float* bmix = (const float*)d_in[8];
  const float* kgam = (const float*)d_in[9];
  const float* ffw  = (const float*)d_in[10];
  const float* Win  = (const float*)d_in[11];
  const float* bin  = (const float*)d_in[12];
  const float* Wout = (const float*)d_in[13];
  const float* bout = (const float*)d_in[14];
  const float* vrw  = (const float*)d_in[15];
  const float* vrW  = (const float*)d_in[16];
  const float* fnw  = (const float*)d_in[17];

  const size_t NT = (size_t)NTOK * DIM;   // 12,582,912
  float* ws  = (float*)d_ws;
  float* x   = ws;                        // NT f32
  float* mix = x + NT;                    // NTOK*12
  float* gate = mix + (size_t)NTOK * HEADS;
  unsigned short* tn   = (unsigned short*)(gate + (size_t)NTOK * HEADS); // NT bf16
  unsigned short* qkv  = tn + NT;                        // NTOK*2304 bf16
  unsigned short* rvb  = qkv + (size_t)NTOK * LDQ;       // NT bf16
  unsigned short* wqkvT = rvb + NT;                      // 2304*768
  unsigned short* woT  = wqkvT + (size_t)2304 * 768;     // 768*768
  unsigned short* winT = woT + (size_t)768 * 768;        // 4096*768 (glu-interleaved)
  unsigned short* woutT= winT + (size_t)4096 * 768;      // 768*2048
  unsigned short* vrWT = woutT + (size_t)768 * 2048;     // 768*768
  unsigned short* hg   = qkv;   // FF hidden [NTOK][2048] aliases qkv

  hipMemcpyAsync(x, tokens, NT * sizeof(float), hipMemcpyDeviceToDevice, stream);

  // value residual: rvb = bf16(rmsnorm(tokens, vrw) @ vrW)
  w_to_bt<<<dim3(24, 24), 256, 0, stream>>>(vrW, vrWT, DIM, DIM);
  rmsnorm_kernel<1><<<NTOK, 256, 0, stream>>>(tokens, vrw, tn);
  gemm_bf16<2><<<dim3(6, 128), 256, 0, stream>>>(
      tn, vrWT, nullptr, rvb, nullptr, NTOK, DIM, DIM);

  for (int i = 0; i < DEPTH; ++i) {
    int is_time = ((i + 1) % 4 == 0) ? 1 : 0;
    // all per-layer weight conversion in one dispatch
    w_convert_layer<<<6912, 256, 0, stream>>>(
        Wq + (size_t)i * DIM * DIM, Wk + (size_t)i * DIM * DIM,
        Wv + (size_t)i * DIM * DIM, Wo + (size_t)i * DIM * DIM,
        Win + (size_t)i * DIM * 2 * DFF, Wout + (size_t)i * DFF * DIM,
        wqkvT, woT, winT, woutT);

    rmsnorm_kernel<1><<<NTOK, 256, 0, stream>>>(x, attn_norm_w + (size_t)i * DIM, tn);
    // fused qkv projection -> packed bf16 [tok][2304]
    gemm_bf16<2><<<dim3(18, 128), 256, 0, stream>>>(
        tn, wqkvT, nullptr, qkv, nullptr, NTOK, LDQ, DIM);
    proj12x2_kernel<<<NTOK / 4, 256, 0, stream>>>(
        tn, Wmix + (size_t)i * DIM * HEADS, bmix + (size_t)i * HEADS,
        Wg + (size_t)i * DIM * HEADS, mix, gate);
    if (is_time) {
      qkv_fix_kernel<<<dim3(NTOK), 768, 0, stream>>>(
          qkv, rvb, mix, kgam + (size_t)i * HEADS * DH, is_time);
      attn_time_mfma<<<dim3((BB * SS) / 4, HEADS), 256, 0, stream>>>(
          qkv, qkv + 768, qkv + 1536, gate, tn);
    } else {
      attn_mfma_kernel<<<dim3(BB * TT * 2, HEADS), 256, 0, stream>>>(
          qkv, qkv + 768, qkv + 1536, rvb, mix, gate,
          kgam + (size_t)i * HEADS * DH, tn);
    }
    gemm_bf16<1><<<dim3(6, 128), 256, 0, stream>>>(tn, woT, x, nullptr, nullptr, NTOK, DIM, DIM);
    // FF: rmsnorm -> glu-interleaved in-proj (MODE 3) -> out-proj
    rmsnorm_kernel<1><<<NTOK, 256, 0, stream>>>(x, ffw + (size_t)i * DIM, tn);
    gemm_bf16<3><<<dim3(32, 128), 256, 0, stream>>>(
        tn, winT, nullptr, hg, bin + (size_t)i * 2 * DFF, NTOK, 2 * DFF, DIM);
    gemm_bf16<1><<<dim3(6, 128), 256, 0, stream>>>(
        hg, woutT, x, nullptr, bout + (size_t)i * DIM, NTOK, DIM, DFF);
  }
  rmsnorm_kernel<0><<<NTOK, 256, 0, stream>>>(x, fnw, (float*)d_out);
}

// Round 7
// 4429.364 us; speedup vs baseline: 1.1594x; 1.0147x over previous
//
#include <hip/hip_runtime.h>
#include <cmath>

#define DIM 768
#define DEPTH 8
#define HEADS 12
#define DH 64
#define DFF 2048
#define NTOK 16384   // B*T*S = 2*32*256
#define BB 2
#define TT 32
#define SS 256
#define LDQ 2304     // packed qkv row stride (3*768)

typedef __attribute__((ext_vector_type(8))) short short8;
typedef __attribute__((ext_vector_type(4))) float f32x4;

__device__ __forceinline__ float sigmoidf_(float x) { return 1.0f / (1.0f + __expf(-x)); }
// gelu via A&S 7.1.26 erf (max abs err ~1.5e-7, ~half the VALU of libm erff)
__device__ __forceinline__ float geluf_(float x) {
  float z = fabsf(x) * 0.70710678118654752f;
  float t = __builtin_amdgcn_rcpf(fmaf(0.3275911f, z, 1.0f));
  float poly = t * fmaf(t, fmaf(t, fmaf(t, fmaf(t, 1.061405429f, -1.453152027f),
                    1.421413741f), -0.284496736f), 0.254829592f);
  float erfv = 1.0f - poly * __expf(-z * z);
  erfv = copysignf(erfv, x);
  return 0.5f * x * (1.0f + erfv);
}
__device__ __forceinline__ unsigned short f2bf(float x) {
  union { float f; unsigned int u; } a; a.f = x;
  unsigned int r = a.u + 0x7fff + ((a.u >> 16) & 1);   // RNE
  return (unsigned short)(r >> 16);
}
__device__ __forceinline__ float bf2f(unsigned short h) {
  union { unsigned int u; float f; } a; a.u = ((unsigned int)h) << 16;
  return a.f;
}
__device__ __forceinline__ void load_lds16(const void* g, void* l) {
  __builtin_amdgcn_global_load_lds(
      (const __attribute__((address_space(1))) unsigned int*)g,
      (__attribute__((address_space(3))) unsigned int*)l, 16, 0, 0);
}
// softclamp+exp: p = exp(50*tanh(sv/50)) = 2^72.1347 * 2^(-144.2695/(e^{sv/25}+1))
__device__ __forceinline__ float softclamp_exp(float sv) {
  float a = exp2f(sv * 0.057707802f);
  float rc = __builtin_amdgcn_rcpf(a + 1.0f);
  return exp2f(fmaf(-144.26950408f, rc, 72.13475204f));
}

// ---------------- RMSNorm: one block per row of 768 ----------------
template<int BF>
__global__ __launch_bounds__(256) void rmsnorm_kernel(
    const float* __restrict__ x, const float* __restrict__ w, void* __restrict__ outp)
{
  int row = blockIdx.x;
  int tid = threadIdx.x;
  const float* xr = x + (size_t)row * DIM;
  float v0 = xr[tid], v1 = xr[tid + 256], v2 = xr[tid + 512];
  float ss = v0 * v0 + v1 * v1 + v2 * v2;
  #pragma unroll
  for (int off = 32; off; off >>= 1) ss += __shfl_xor(ss, off);
  __shared__ float sred[4];
  if ((tid & 63) == 0) sred[tid >> 6] = ss;
  __syncthreads();
  float tot = sred[0] + sred[1] + sred[2] + sred[3];
  float r = rsqrtf(tot * (1.0f / DIM) + 1e-6f);
  if (BF) {
    unsigned short* orow = (unsigned short*)outp + (size_t)row * DIM;
    orow[tid]       = f2bf(v0 * r * w[tid]);
    orow[tid + 256] = f2bf(v1 * r * w[tid + 256]);
    orow[tid + 512] = f2bf(v2 * r * w[tid + 512]);
  } else {
    float* orow = (float*)outp + (size_t)row * DIM;
    orow[tid]       = v0 * r * w[tid];
    orow[tid + 256] = v1 * r * w[tid + 256];
    orow[tid + 512] = v2 * r * w[tid + 512];
  }
}

// ---------------- weight convert+transpose: W[K][N] f32 -> WT[N][K] bf16 ----------------
__global__ __launch_bounds__(256) void w_to_bt(
    const float* __restrict__ W, unsigned short* __restrict__ WT, int K, int N)
{
  __shared__ float t[32][33];
  int n0 = blockIdx.x * 32, k0 = blockIdx.y * 32;
  int c = threadIdx.x & 31, r8 = threadIdx.x >> 5;
  #pragma unroll
  for (int rr = r8; rr < 32; rr += 8)
    t[rr][c] = W[(size_t)(k0 + rr) * N + n0 + c];
  __syncthreads();
  #pragma unroll
  for (int rn = r8; rn < 32; rn += 8)
    WT[(size_t)(n0 + rn) * K + k0 + c] = f2bf(t[c][rn]);
}

// ---------------- per-layer weight conversion, single dispatch ----------------
// regions: [0,1728) qkv (3x 24x24 tiles), [1728,2304) wo, [2304,5376) win
// (glu-interleaved: out row n' <- src col b*16+r (r<16) or 2048+b*16+r-16, b=n'>>5),
// [5376,6912) wout
__global__ __launch_bounds__(256) void w_convert_layer(
    const float* __restrict__ Wq, const float* __restrict__ Wk,
    const float* __restrict__ Wv, const float* __restrict__ Wo,
    const float* __restrict__ Win, const float* __restrict__ Wout,
    unsigned short* __restrict__ wqkvT, unsigned short* __restrict__ woT,
    unsigned short* __restrict__ winT, unsigned short* __restrict__ woutT)
{
  __shared__ float tle[32][33];
  int t = blockIdx.x;
  const float* W; unsigned short* WT; int K, N, n0, k0, glu = 0;
  if (t < 1728) {
    int rg = t / 576, tt = t - rg * 576;
    W = (rg == 0) ? Wq : (rg == 1) ? Wk : Wv;
    WT = wqkvT + (size_t)rg * 768 * 768;
    K = 768; N = 768; n0 = (tt % 24) * 32; k0 = (tt / 24) * 32;
  } else if (t < 2304) {
    int tt = t - 1728; W = Wo; WT = woT;
    K = 768; N = 768; n0 = (tt % 24) * 32; k0 = (tt / 24) * 32;
  } else if (t < 5376) {
    int tt = t - 2304; W = Win; WT = winT;
    K = 768; N = 4096; n0 = (tt % 128) * 32; k0 = (tt / 128) * 32; glu = 1;
  } else {
    int tt = t - 5376; W = Wout; WT = woutT;
    K = 2048; N = 768; n0 = (tt % 24) * 32; k0 = (tt / 24) * 32;
  }
  int c = threadIdx.x & 31, r8 = threadIdx.x >> 5;
  int col = n0 + c;
  int scol = col;
  if (glu) {
    int b = col >> 5, rr2 = col & 31;
    scol = (rr2 < 16) ? (b * 16 + rr2) : (2048 + b * 16 + rr2 - 16);
  }
  for (int rr = r8; rr < 32; rr += 8)
    tle[rr][c] = W[(size_t)(k0 + rr) * N + scol];
  __syncthreads();
  for (int rn = r8; rn < 32; rn += 8)
    WT[(size_t)(n0 + rn) * K + k0 + c] = f2bf(tle[c][rn]);
}

// ---------------- bf16 MFMA GEMM: 128x128 tile, BK=64, XOR-swizzled LDS ----------------
// A: MxK bf16 row-major. BT: NxK bf16 row-major (= B transposed). K % 64 == 0.
// LDS layout: row-major [128][64] ush; 16B unit u of row r stored at unit u^(r&7)
// (source pre-swizzle for global_load_lds; same XOR on ds_read -> conflict-free:
// consecutive lanes hit 8 distinct 4-bank groups).
// MODE 0: Cf = A@B (+bias)            (fp32 out)
// MODE 1: Cf += A@B (+bias)           (fp32 accumulate)
// MODE 2: Hg = bf16(A@B + bias)       (bf16 out)
// MODE 3: glu-interleaved B (16-col a/g blocks): Hg[M][N/2] = bf16(a * gelu(g))
template<int MODE>
__global__ __launch_bounds__(256) void gemm_bf16(
    const unsigned short* __restrict__ A, const unsigned short* __restrict__ BT,
    float* __restrict__ Cf, unsigned short* __restrict__ Hg,
    const float* __restrict__ bias, int M, int N, int K)
{
  __shared__ unsigned short As[128 * 64];
  __shared__ unsigned short Bs[128 * 64];
  const int tid = threadIdx.x;
  const int wave = tid >> 6;
  const int lane = tid & 63;
  const int bm = blockIdx.y * 128;
  const int bn = blockIdx.x * 128;
  const int wm = (wave & 1) * 64;
  const int wn = (wave >> 1) * 64;

  f32x4 acc[4][4];
  #pragma unroll
  for (int i = 0; i < 4; ++i)
    #pragma unroll
    for (int j = 0; j < 4; ++j) acc[i][j] = (f32x4){0.f, 0.f, 0.f, 0.f};

  // staging: slot f = it*256 + wave*64 + lane -> row = f>>3 (= it*32 + wave*8 + lane>>3),
  // dest unit = lane&7; source k-unit = (lane&7) ^ (row&7), row&7 = lane>>3.
  const int srow = wave * 8 + (lane >> 3);
  const int sku = ((lane & 7) ^ (lane >> 3)) * 8;      // ushorts
  const unsigned short* gA = A + (size_t)(bm + srow) * K + sku;
  const unsigned short* gB = BT + (size_t)(bn + srow) * K + sku;
  unsigned short* lA = &As[wave * 512];                // + it*2048
  unsigned short* lB = &Bs[wave * 512];

  const int fr = lane & 15;
  const int fg = lane >> 4;

  for (int k0 = 0; k0 < K; k0 += 64) {
    #pragma unroll
    for (int it = 0; it < 4; ++it) {
      load_lds16(gA + k0 + (size_t)(it * 32) * K, lA + it * 2048);
      load_lds16(gB + k0 + (size_t)(it * 32) * K, lB + it * 2048);
    }
    __syncthreads();
    #pragma unroll
    for (int s = 0; s < 2; ++s) {
      short8 a[4], b[4];
      #pragma unroll
      for (int i = 0; i < 4; ++i) {
        int row = wm + 16 * i + fr;
        a[i] = *(const short8*)&As[row * 64 + (((s * 4 + fg) ^ (row & 7)) << 3)];
      }
      #pragma unroll
      for (int j = 0; j < 4; ++j) {
        int row = wn + 16 * j + fr;
        b[j] = *(const short8*)&Bs[row * 64 + (((s * 4 + fg) ^ (row & 7)) << 3)];
      }
      #pragma unroll
      for (int i = 0; i < 4; ++i)
        #pragma unroll
        for (int j = 0; j < 4; ++j)
          acc[i][j] = __builtin_amdgcn_mfma_f32_16x16x32_bf16(a[i], b[j], acc[i][j], 0, 0, 0);
    }
    __syncthreads();
  }

  const int crow0 = bm + wm + (lane >> 4) * 4;
  const int ccol0 = bn + wn + fr;
  float bv[4];
  if (MODE != 3) {
    #pragma unroll
    for (int j = 0; j < 4; ++j) bv[j] = bias ? bias[ccol0 + 16 * j] : 0.0f;
  }
  #pragma unroll
  for (int i = 0; i < 4; ++i) {
    #pragma unroll
    for (int r = 0; r < 4; ++r) {
      int row = crow0 + 16 * i + r;
      if (MODE == 3) {
        #pragma unroll
        for (int pj = 0; pj < 2; ++pj) {
          int b32 = (bn + wn + 32 * pj) >> 5;
          float av = acc[i][2 * pj][r] + bias[b32 * 16 + fr];
          float gv = acc[i][2 * pj + 1][r] + bias[2048 + b32 * 16 + fr];
          Hg[(size_t)row * (N >> 1) + b32 * 16 + fr] = f2bf(av * geluf_(gv));
        }
      } else {
        #pragma unroll
        for (int j = 0; j < 4; ++j) {
          int col = ccol0 + 16 * j;
          size_t idx = (size_t)row * N + col;
          float val = acc[i][j][r] + bv[j];
          if (MODE == 0) Cf[idx] = val;
          else if (MODE == 1) Cf[idx] += val;
          else Hg[idx] = f2bf(val);
        }
      }
    }
  }
}

// ---------------- N=12 dual projection + sigmoid (mix & gate in one pass) ----------------
__global__ __launch_bounds__(256) void proj12x2_kernel(
    const unsigned short* __restrict__ A, const float* __restrict__ Bw1,
    const float* __restrict__ b1, const float* __restrict__ Bw2,
    float* __restrict__ out1, float* __restrict__ out2)
{
  int row = blockIdx.x * 4 + (threadIdx.x >> 6);
  int lane = threadIdx.x & 63;
  const unsigned short* ar = A + (size_t)row * DIM;
  float acc1[HEADS], acc2[HEADS];
  #pragma unroll
  for (int j = 0; j < HEADS; ++j) { acc1[j] = 0.0f; acc2[j] = 0.0f; }
  for (int k2 = lane; k2 < DIM; k2 += 64) {
    float a = bf2f(ar[k2]);
    const float* bw1 = Bw1 + (size_t)k2 * HEADS;
    const float* bw2 = Bw2 + (size_t)k2 * HEADS;
    #pragma unroll
    for (int j = 0; j < HEADS; ++j) {
      acc1[j] = fmaf(a, bw1[j], acc1[j]);
      acc2[j] = fmaf(a, bw2[j], acc2[j]);
    }
  }
  #pragma unroll
  for (int j = 0; j < HEADS; ++j) {
    #pragma unroll
    for (int off = 32; off; off >>= 1) {
      acc1[j] += __shfl_xor(acc1[j], off);
      acc2[j] += __shfl_xor(acc2[j], off);
    }
  }
  if (lane < HEADS) {
    out1[(size_t)row * HEADS + lane] = sigmoidf_(acc1[lane] + b1[lane]);
    out2[(size_t)row * HEADS + lane] = sigmoidf_(acc2[lane]);
  }
}

// ---------------- qkv postprocess (time layers only): v-lerp, k-norm+gamma, rotary ----------------
__global__ __launch_bounds__(768) void qkv_fix_kernel(
    unsigned short* __restrict__ qkv, const unsigned short* __restrict__ rvb,
    const float* __restrict__ mix, const float* __restrict__ kgam, int is_time)
{
  int tok = blockIdx.x;
  int h = threadIdx.x >> 6;
  int d = threadIdx.x & 63;
  size_t rowb = (size_t)tok * LDQ + h * DH + d;
  float kv = bf2f(qkv[rowb + 768]);
  float ss = kv * kv;
  #pragma unroll
  for (int off = 32; off; off >>= 1) ss += __shfl_xor(ss, off);
  float nrm = fmaxf(sqrtf(ss), 1e-12f);
  kv = kv / nrm * (kgam[h * DH + d] + 1.0f) * 8.0f;   // sqrt(DH)=8
  float mv = mix[(size_t)tok * HEADS + h];
  float vv = bf2f(qkv[rowb + 1536]);
  float rvv = bf2f(rvb[(size_t)tok * DIM + h * DH + d]);
  qkv[rowb + 1536] = f2bf(vv + mv * (rvv - vv));
  float qv = bf2f(qkv[rowb]);
  if (is_time) {
    int t = (tok >> 8) & 31;          // token = (b*32+t)*256+s
    int j = d & 31;
    float ang = (float)t * __expf(-(float)j * (9.210340371976184f / 32.0f));
    float cs = cosf(ang), sn = sinf(ang);
    float qp = __shfl_xor(qv, 32);
    float kp = __shfl_xor(kv, 32);
    float sgn = (d < 32) ? -1.0f : 1.0f;
    qv = qv * cs + sgn * qp * sn;
    kv = kv * cs + sgn * kp * sn;
  }
  qkv[rowb] = f2bf(qv);
  qkv[rowb + 768] = f2bf(kv);
}

// ---------------- MFMA space attention, qkv-fix fused into staging ----------------
// grid (BB*TT*2, HEADS): block = 128 q-rows of one (seq bp, head h); wave = 32 q-rows.
// K staged with l2norm*(gamma+1)*8 applied; V staged with value-residual lerp.
// launch_bounds(256,2): cap 256 VGPR — the (256,3) cap of 170 forced scratch spill
// (rounds 2-4: WRITE_SIZE 249MB vs 25MB output). S computed in 32-col sub-chunks
// to keep peak pressure ~16 regs lower.
__global__ __launch_bounds__(256, 2) void attn_mfma_kernel(
    const unsigned short* __restrict__ q, const unsigned short* __restrict__ k,
    const unsigned short* __restrict__ v, const unsigned short* __restrict__ rvb,
    const float* __restrict__ mix, const float* __restrict__ gate,
    const float* __restrict__ kgam, unsigned short* __restrict__ o)
{
  __shared__ __align__(16) unsigned short Ks[128 * 64];    // 16 KB, u^=row&7
  __shared__ __align__(16) unsigned short VsT[64 * 128];   // 16 KB, u^=d&15
  __shared__ __align__(16) unsigned short Pw[4][32 * 64];  // 16 KB, u^=row&7
  const int tid = threadIdx.x;
  const int wave = tid >> 6;
  const int lane = tid & 63;
  const int g = lane >> 4;
  const int c16 = lane & 15;
  const int bp = blockIdx.x >> 1;
  const int qh = blockIdx.x & 1;
  const int h = blockIdx.y;
  const size_t qoff = (size_t)bp * SS * LDQ + h * DH;
  const int qbase = qh * 128 + wave * 32;

  // Q fragments: wave owns rows [qbase, qbase+32)
  short8 aq[2][2];
  #pragma unroll
  for (int i = 0; i < 2; ++i) {
    const unsigned short* qp = q + qoff + (size_t)(qbase + i * 16 + c16) * LDQ;
    #pragma unroll
    for (int cc = 0; cc < 2; ++cc)
      aq[i][cc] = *(const short8*)(qp + cc * 32 + g * 8);
  }

  f32x4 oacc[2][4];
  float rs[2][4];
  #pragma unroll
  for (int i = 0; i < 2; ++i)
    #pragma unroll
    for (int j = 0; j < 4; ++j) {
      oacc[i][j] = (f32x4){0.f, 0.f, 0.f, 0.f};
      rs[i][j] = 0.f;
    }

  for (int half = 0; half < 2; ++half) {
    const int r0 = half * 128;
    // ---- stage K rows [r0,r0+128) with k-norm+gamma fused ----
    #pragma unroll
    for (int it = 0; it < 4; ++it) {
      int f = tid + it * 256;
      int row = f >> 3, u = f & 7;
      short8 t8 = *(const short8*)(k + qoff + (size_t)(r0 + row) * LDQ + u * 8);
      float kv[8];
      float ss = 0.f;
      #pragma unroll
      for (int c = 0; c < 8; ++c) { kv[c] = bf2f((unsigned short)t8[c]); ss += kv[c] * kv[c]; }
      ss += __shfl_xor(ss, 1); ss += __shfl_xor(ss, 2); ss += __shfl_xor(ss, 4);
      float inv = 8.0f / fmaxf(sqrtf(ss), 1e-12f);   // sqrt(DH)=8 folded in
      float4 kg0 = *(const float4*)(kgam + h * DH + u * 8);
      float4 kg1 = *(const float4*)(kgam + h * DH + u * 8 + 4);
      short8 o8;
      o8[0] = (short)f2bf(kv[0] * inv * (kg0.x + 1.0f));
      o8[1] = (short)f2bf(kv[1] * inv * (kg0.y + 1.0f));
      o8[2] = (short)f2bf(kv[2] * inv * (kg0.z + 1.0f));
      o8[3] = (short)f2bf(kv[3] * inv * (kg0.w + 1.0f));
      o8[4] = (short)f2bf(kv[4] * inv * (kg1.x + 1.0f));
      o8[5] = (short)f2bf(kv[5] * inv * (kg1.y + 1.0f));
      o8[6] = (short)f2bf(kv[6] * inv * (kg1.z + 1.0f));
      o8[7] = (short)f2bf(kv[7] * inv * (kg1.w + 1.0f));
      *(short8*)&Ks[row * 64 + ((u ^ (row & 7)) << 3)] = o8;
    }
    // ---- stage V transposed with value-residual lerp fused ----
    #pragma unroll
    for (int it = 0; it < 4; ++it) {
      int f = tid + it * 256;
      int j = f & 127, dq = f >> 7;
      int tok = bp * SS + r0 + j;
      short8 v8 = *(const short8*)(v + qoff + (size_t)(r0 + j) * LDQ + dq * 8);
      short8 r8 = *(const short8*)(rvb + (size_t)tok * DIM + h * DH + dq * 8);
      float mv = mix[(size_t)tok * HEADS + h];
      int u = j >> 3;
      #pragma unroll
      for (int c = 0; c < 8; ++c) {
        int d = dq * 8 + c;
        float vv = bf2f((unsigned short)v8[c]);
        float val = vv + mv * (bf2f((unsigned short)r8[c]) - vv);
        VsT[d * 128 + ((u ^ (d & 15)) << 3) + (j & 7)] = f2bf(val);
      }
    }
    __syncthreads();

    #pragma unroll
    for (int jc = 0; jc < 2; ++jc) {
      const int lr0 = jc * 64;
      // ---- S = Q K^T + softmax, 32-col sub-chunks (low register pressure) ----
      #pragma unroll
      for (int jh = 0; jh < 2; ++jh) {
        f32x4 s[2][2];
        #pragma unroll
        for (int i = 0; i < 2; ++i)
          #pragma unroll
          for (int j = 0; j < 2; ++j) s[i][j] = (f32x4){0.f, 0.f, 0.f, 0.f};
        #pragma unroll
        for (int j2 = 0; j2 < 2; ++j2) {
          int jt = jh * 2 + j2;
          int row = lr0 + jt * 16 + c16;
          short8 b0 = *(const short8*)&Ks[row * 64 + ((g ^ (row & 7)) << 3)];
          short8 b1 = *(const short8*)&Ks[row * 64 + (((4 + g) ^ (row & 7)) << 3)];
          #pragma unroll
          for (int i = 0; i < 2; ++i) {
            s[i][j2] = __builtin_amdgcn_mfma_f32_16x16x32_bf16(aq[i][0], b0, s[i][j2], 0, 0, 0);
            s[i][j2] = __builtin_amdgcn_mfma_f32_16x16x32_bf16(aq[i][1], b1, s[i][j2], 0, 0, 0);
          }
        }
        #pragma unroll
        for (int i = 0; i < 2; ++i) {
          #pragma unroll
          for (int j2 = 0; j2 < 2; ++j2) {
            int pj = (jh * 2 + j2) * 16 + c16;
            int uj = pj >> 3;
            #pragma unroll
            for (int r = 0; r < 4; ++r) {
              float p = softclamp_exp(s[i][j2][r] * 0.125f);
              unsigned short pb = f2bf(p);
              rs[i][r] += bf2f(pb);
              int prow = i * 16 + g * 4 + r;
              Pw[wave][prow * 64 + ((uj ^ (prow & 7)) << 3) + (pj & 7)] = pb;
            }
          }
        }
      }
      // ---- O += P V ----
      #pragma unroll
      for (int jj = 0; jj < 2; ++jj) {
        short8 pa[2];
        #pragma unroll
        for (int i = 0; i < 2; ++i) {
          int prow = i * 16 + c16;
          int u = jj * 4 + g;
          pa[i] = *(const short8*)&Pw[wave][prow * 64 + ((u ^ (prow & 7)) << 3)];
        }
        const int jl = lr0 + jj * 32 + g * 8;
        const int uv = jl >> 3;
        #pragma unroll
        for (int dt = 0; dt < 4; ++dt) {
          int d = dt * 16 + c16;
          short8 bv = *(const short8*)&VsT[d * 128 + ((uv ^ (d & 15)) << 3)];
          #pragma unroll
          for (int i = 0; i < 2; ++i)
            oacc[i][dt] = __builtin_amdgcn_mfma_f32_16x16x32_bf16(pa[i], bv, oacc[i][dt], 0, 0, 0);
        }
      }
    }
    __syncthreads();
  }

  #pragma unroll
  for (int i = 0; i < 2; ++i)
    #pragma unroll
    for (int r = 0; r < 4; ++r) {
      float t = rs[i][r];
      t += __shfl_xor(t, 1); t += __shfl_xor(t, 2);
      t += __shfl_xor(t, 4); t += __shfl_xor(t, 8);
      rs[i][r] = t;
    }
  #pragma unroll
  for (int i = 0; i < 2; ++i) {
    #pragma unroll
    for (int r = 0; r < 4; ++r) {
      int row = qbase + i * 16 + g * 4 + r;
      int tq = bp * SS + row;
      float gt = gate[(size_t)tq * HEADS + h] / rs[i][r];
      unsigned short* op = o + (size_t)tq * DIM + h * DH;
      #pragma unroll
      for (int dt = 0; dt < 4; ++dt)
        op[dt * 16 + c16] = f2bf(oacc[i][dt][r] * gt);
    }
  }
}

// ---------------- MFMA time attention (bf16 in): wave = one (b,s) sequence ----------------
__global__ __launch_bounds__(256, 2) void attn_time_mfma(
    const unsigned short* __restrict__ q, const unsigned short* __restrict__ k,
    const unsigned short* __restrict__ v, const float* __restrict__ gate,
    unsigned short* __restrict__ o)
{
  __shared__ __align__(16) unsigned short VT[4][64 * 32];  // [d][t'], u^=d&3
  __shared__ __align__(16) unsigned short Pw[4][32 * 32];  // [t][t'], u^=t&3
  const int tid = threadIdx.x;
  const int wave = tid >> 6;
  const int lane = tid & 63;
  const int g = lane >> 4;
  const int c16 = lane & 15;
  const int h = blockIdx.y;
  const int sp = blockIdx.x * 4 + wave;                 // 0..511
  const int base = (sp >> 8) * (TT * SS) + (sp & 255);  // b*8192 + s

  short8 aq[2][2], bk[2][2];
  #pragma unroll
  for (int i = 0; i < 2; ++i) {
    const unsigned short* qp = q + (size_t)(base + (i * 16 + c16) * SS) * LDQ + h * DH;
    const unsigned short* kp = k + (size_t)(base + (i * 16 + c16) * SS) * LDQ + h * DH;
    #pragma unroll
    for (int cc = 0; cc < 2; ++cc) {
      aq[i][cc] = *(const short8*)(qp + cc * 32 + g * 8);
      bk[i][cc] = *(const short8*)(kp + cc * 32 + g * 8);
    }
  }

  // stage V transposed: lane handles t' = lane>>1, d-half = (lane&1)*32
  {
    int tp = lane >> 1;
    int dh0 = (lane & 1) * 32;
    const unsigned short* vp = v + (size_t)(base + tp * SS) * LDQ + h * DH + dh0;
    int ut = tp >> 3;
    #pragma unroll
    for (int j4 = 0; j4 < 4; ++j4) {
      short8 t = *(const short8*)(vp + j4 * 8);
      #pragma unroll
      for (int c = 0; c < 8; ++c) {
        int d = dh0 + j4 * 8 + c;
        VT[wave][d * 32 + ((ut ^ (d & 3)) << 3) + (tp & 7)] = (unsigned short)t[c];
      }
    }
  }

  // S = Q K^T (32x32)
  f32x4 s[2][2];
  #pragma unroll
  for (int i = 0; i < 2; ++i)
    #pragma unroll
    for (int j = 0; j < 2; ++j) s[i][j] = (f32x4){0.f, 0.f, 0.f, 0.f};
  #pragma unroll
  for (int jt = 0; jt < 2; ++jt)
    #pragma unroll
    for (int i = 0; i < 2; ++i) {
      s[i][jt] = __builtin_amdgcn_mfma_f32_16x16x32_bf16(aq[i][0], bk[jt][0], s[i][jt], 0, 0, 0);
      s[i][jt] = __builtin_amdgcn_mfma_f32_16x16x32_bf16(aq[i][1], bk[jt][1], s[i][jt], 0, 0, 0);
    }

  // softclamp + exp + causal mask; bf16 P to wave-private LDS
  float rs[2][4];
  #pragma unroll
  for (int i = 0; i < 2; ++i)
    #pragma unroll
    for (int r = 0; r < 4; ++r) rs[i][r] = 0.f;
  #pragma unroll
  for (int i = 0; i < 2; ++i) {
    #pragma unroll
    for (int jt = 0; jt < 2; ++jt) {
      int pj = jt * 16 + c16;
      int uj = pj >> 3;
      #pragma unroll
      for (int r = 0; r < 4; ++r) {
        int t = i * 16 + g * 4 + r;
        float p = softclamp_exp(s[i][jt][r] * 0.125f);
        unsigned short pb = (pj <= t) ? f2bf(p) : (unsigned short)0;
        rs[i][r] += bf2f(pb);
        Pw[wave][t * 32 + ((uj ^ (t & 3)) << 3) + (pj & 7)] = pb;
      }
    }
  }

  // O = P V
  short8 pa[2];
  #pragma unroll
  for (int i = 0; i < 2; ++i) {
    int prow = i * 16 + c16;
    pa[i] = *(const short8*)&Pw[wave][prow * 32 + ((g ^ (prow & 3)) << 3)];
  }
  f32x4 oacc[2][4];
  #pragma unroll
  for (int dt = 0; dt < 4; ++dt) {
    int d = dt * 16 + c16;
    short8 bv = *(const short8*)&VT[wave][d * 32 + ((g ^ (d & 3)) << 3)];
    #pragma unroll
    for (int i = 0; i < 2; ++i)
      oacc[i][dt] = __builtin_amdgcn_mfma_f32_16x16x32_bf16(
          pa[i], bv, (f32x4){0.f, 0.f, 0.f, 0.f}, 0, 0, 0);
  }

  #pragma unroll
  for (int i = 0; i < 2; ++i)
    #pragma unroll
    for (int r = 0; r < 4; ++r) {
      float t = rs[i][r];
      t += __shfl_xor(t, 1); t += __shfl_xor(t, 2);
      t += __shfl_xor(t, 4); t += __shfl_xor(t, 8);
      rs[i][r] = t;
    }
  #pragma unroll
  for (int i = 0; i < 2; ++i) {
    #pragma unroll
    for (int r = 0; r < 4; ++r) {
      int t = i * 16 + g * 4 + r;
      int tok = base + t * SS;
      float gt = gate[(size_t)tok * HEADS + h] / rs[i][r];
      unsigned short* op = o + (size_t)tok * DIM + h * DH;
      #pragma unroll
      for (int dt = 0; dt < 4; ++dt)
        op[dt * 16 + c16] = f2bf(oacc[i][dt][r] * gt);
    }
  }
}

// ---------------- driver ----------------
extern "C" void kernel_launch(void* const* d_in, const int* in_sizes, int n_in,
                              void* d_out, int out_size, void* d_ws, size_t ws_size,
                              hipStream_t stream)
{
  const float* tokens = (const float*)d_in[0];
  const float* attn_norm_w = (const float*)d_in[1];
  const float* Wq   = (const float*)d_in[2];
  const float* Wk   = (const float*)d_in[3];
  const float* Wv   = (const float*)d_in[4];
  const float* Wo   = (const float*)d_in[5];
  const float* Wg   = (const float*)d_in[6];
  const float* Wmix = (const float*)d_in[7];
  const float* bmix = (const float*)d_in[8];
  const float* kgam = (const float*)d_in[9];
  const float* ffw  = (const float*)d_in[10];
  const float* Win  = (const float*)d_in[11];
  const float* bin  = (const float*)d_in[12];
  const float* Wout = (const float*)d_in[13];
  const float* bout = (const float*)d_in[14];
  const float* vrw  = (const float*)d_in[15];
  const float* vrW  = (const float*)d_in[16];
  const float* fnw  = (const float*)d_in[17];

  const size_t NT = (size_t)NTOK * DIM;   // 12,582,912
  float* ws  = (float*)d_ws;
  float* x   = ws;                        // NT f32
  float* mix = x + NT;                    // NTOK*12
  float* gate = mix + (size_t)NTOK * HEADS;
  unsigned short* tn   = (unsigned short*)(gate + (size_t)NTOK * HEADS); // NT bf16
  unsigned short* qkv  = tn + NT;                        // NTOK*2304 bf16
  unsigned short* rvb  = qkv + (size_t)NTOK * LDQ;       // NT bf16
  unsigned short* wqkvT = rvb + NT;                      // 2304*768
  unsigned short* woT  = wqkvT + (size_t)2304 * 768;     // 768*768
  unsigned short* winT = woT + (size_t)768 * 768;        // 4096*768 (glu-interleaved)
  unsigned short* woutT= winT + (size_t)4096 * 768;      // 768*2048
  unsigned short* vrWT = woutT + (size_t)768 * 2048;     // 768*768
  unsigned short* hg   = qkv;   // FF hidden [NTOK][2048] aliases qkv

  hipMemcpyAsync(x, tokens, NT * sizeof(float), hipMemcpyDeviceToDevice, stream);

  // value residual: rvb = bf16(rmsnorm(tokens, vrw) @ vrW)
  w_to_bt<<<dim3(24, 24), 256, 0, stream>>>(vrW, vrWT, DIM, DIM);
  rmsnorm_kernel<1><<<NTOK, 256, 0, stream>>>(tokens, vrw, tn);
  gemm_bf16<2><<<dim3(6, 128), 256, 0, stream>>>(
      tn, vrWT, nullptr, rvb, nullptr, NTOK, DIM, DIM);

  for (int i = 0; i < DEPTH; ++i) {
    int is_time = ((i + 1) % 4 == 0) ? 1 : 0;
    // all per-layer weight conversion in one dispatch
    w_convert_layer<<<6912, 256, 0, stream>>>(
        Wq + (size_t)i * DIM * DIM, Wk + (size_t)i * DIM * DIM,
        Wv + (size_t)i * DIM * DIM, Wo + (size_t)i * DIM * DIM,
        Win + (size_t)i * DIM * 2 * DFF, Wout + (size_t)i * DFF * DIM,
        wqkvT, woT, winT, woutT);

    rmsnorm_kernel<1><<<NTOK, 256, 0, stream>>>(x, attn_norm_w + (size_t)i * DIM, tn);
    // fused qkv projection -> packed bf16 [tok][2304]
    gemm_bf16<2><<<dim3(18, 128), 256, 0, stream>>>(
        tn, wqkvT, nullptr, qkv, nullptr, NTOK, LDQ, DIM);
    proj12x2_kernel<<<NTOK / 4, 256, 0, stream>>>(
        tn, Wmix + (size_t)i * DIM * HEADS, bmix + (size_t)i * HEADS,
        Wg + (size_t)i * DIM * HEADS, mix, gate);
    if (is_time) {
      qkv_fix_kernel<<<dim3(NTOK), 768, 0, stream>>>(
          qkv, rvb, mix, kgam + (size_t)i * HEADS * DH, is_time);
      attn_time_mfma<<<dim3((BB * SS) / 4, HEADS), 256, 0, stream>>>(
          qkv, qkv + 768, qkv + 1536, gate, tn);
    } else {
      attn_mfma_kernel<<<dim3(BB * TT * 2, HEADS), 256, 0, stream>>>(
          qkv, qkv + 768, qkv + 1536, rvb, mix, gate,
          kgam + (size_t)i * HEADS * DH, tn);
    }
    gemm_bf16<1><<<dim3(6, 128), 256, 0, stream>>>(tn, woT, x, nullptr, nullptr, NTOK, DIM, DIM);
    // FF: rmsnorm -> glu-interleaved in-proj (MODE 3) -> out-proj
    rmsnorm_kernel<1><<<NTOK, 256, 0, stream>>>(x, ffw + (size_t)i * DIM, tn);
    gemm_bf16<3><<<dim3(32, 128), 256, 0, stream>>>(
        tn, winT, nullptr, hg, bin + (size_t)i * 2 * DFF, NTOK, 2 * DFF, DIM);
    gemm_bf16<1><<<dim3(6, 128), 256, 0, stream>>>(
        hg, woutT, x, nullptr, bout + (size_t)i * DIM, NTOK, DIM, DFF);
  }
  rmsnorm_kernel<0><<<NTOK, 256, 0, stream>>>(x, fnw, (float*)d_out);
}

// Round 8
// 4367.550 us; speedup vs baseline: 1.1758x; 1.0142x over previous
//
#include <hip/hip_runtime.h>
#include <cmath>

#define DIM 768
#define DEPTH 8
#define HEADS 12
#define DH 64
#define DFF 2048
#define NTOK 16384   // B*T*S = 2*32*256
#define BB 2
#define TT 32
#define SS 256
#define LDQ 2304     // packed qkv row stride (3*768)

typedef __attribute__((ext_vector_type(8))) short short8;
typedef __attribute__((ext_vector_type(4))) float f32x4;

__device__ __forceinline__ float sigmoidf_(float x) { return 1.0f / (1.0f + __expf(-x)); }
// gelu via A&S 7.1.26 erf (max abs err ~1.5e-7)
__device__ __forceinline__ float geluf_(float x) {
  float z = fabsf(x) * 0.70710678118654752f;
  float t = __builtin_amdgcn_rcpf(fmaf(0.3275911f, z, 1.0f));
  float poly = t * fmaf(t, fmaf(t, fmaf(t, fmaf(t, 1.061405429f, -1.453152027f),
                    1.421413741f), -0.284496736f), 0.254829592f);
  float erfv = 1.0f - poly * __expf(-z * z);
  erfv = copysignf(erfv, x);
  return 0.5f * x * (1.0f + erfv);
}
__device__ __forceinline__ unsigned short f2bf(float x) {
  union { float f; unsigned int u; } a; a.f = x;
  unsigned int r = a.u + 0x7fff + ((a.u >> 16) & 1);   // RNE
  return (unsigned short)(r >> 16);
}
__device__ __forceinline__ float bf2f(unsigned short h) {
  union { unsigned int u; float f; } a; a.u = ((unsigned int)h) << 16;
  return a.f;
}
__device__ __forceinline__ void load_lds16(const void* g, void* l) {
  __builtin_amdgcn_global_load_lds(
      (const __attribute__((address_space(1))) unsigned int*)g,
      (__attribute__((address_space(3))) unsigned int*)l, 16, 0, 0);
}
// softclamp+exp: p = exp(50*tanh(sv/50)) = 2^72.1347 * 2^(-144.2695/(e^{sv/25}+1))
__device__ __forceinline__ float softclamp_exp(float sv) {
  float a = exp2f(sv * 0.057707802f);
  float rc = __builtin_amdgcn_rcpf(a + 1.0f);
  return exp2f(fmaf(-144.26950408f, rc, 72.13475204f));
}

// ---------------- RMSNorm: one block per row of 768 ----------------
template<int BF>
__global__ __launch_bounds__(256) void rmsnorm_kernel(
    const float* __restrict__ x, const float* __restrict__ w, void* __restrict__ outp)
{
  int row = blockIdx.x;
  int tid = threadIdx.x;
  const float* xr = x + (size_t)row * DIM;
  float v0 = xr[tid], v1 = xr[tid + 256], v2 = xr[tid + 512];
  float ss = v0 * v0 + v1 * v1 + v2 * v2;
  #pragma unroll
  for (int off = 32; off; off >>= 1) ss += __shfl_xor(ss, off);
  __shared__ float sred[4];
  if ((tid & 63) == 0) sred[tid >> 6] = ss;
  __syncthreads();
  float tot = sred[0] + sred[1] + sred[2] + sred[3];
  float r = rsqrtf(tot * (1.0f / DIM) + 1e-6f);
  if (BF) {
    unsigned short* orow = (unsigned short*)outp + (size_t)row * DIM;
    orow[tid]       = f2bf(v0 * r * w[tid]);
    orow[tid + 256] = f2bf(v1 * r * w[tid + 256]);
    orow[tid + 512] = f2bf(v2 * r * w[tid + 512]);
  } else {
    float* orow = (float*)outp + (size_t)row * DIM;
    orow[tid]       = v0 * r * w[tid];
    orow[tid + 256] = v1 * r * w[tid + 256];
    orow[tid + 512] = v2 * r * w[tid + 512];
  }
}

// ---------------- weight convert+transpose: W[K][N] f32 -> WT[N][K] bf16 ----------------
__global__ __launch_bounds__(256) void w_to_bt(
    const float* __restrict__ W, unsigned short* __restrict__ WT, int K, int N)
{
  __shared__ float t[32][33];
  int n0 = blockIdx.x * 32, k0 = blockIdx.y * 32;
  int c = threadIdx.x & 31, r8 = threadIdx.x >> 5;
  #pragma unroll
  for (int rr = r8; rr < 32; rr += 8)
    t[rr][c] = W[(size_t)(k0 + rr) * N + n0 + c];
  __syncthreads();
  #pragma unroll
  for (int rn = r8; rn < 32; rn += 8)
    WT[(size_t)(n0 + rn) * K + k0 + c] = f2bf(t[c][rn]);
}

// ---------------- per-layer weight conversion, single dispatch ----------------
__global__ __launch_bounds__(256) void w_convert_layer(
    const float* __restrict__ Wq, const float* __restrict__ Wk,
    const float* __restrict__ Wv, const float* __restrict__ Wo,
    const float* __restrict__ Win, const float* __restrict__ Wout,
    unsigned short* __restrict__ wqkvT, unsigned short* __restrict__ woT,
    unsigned short* __restrict__ winT, unsigned short* __restrict__ woutT)
{
  __shared__ float tle[32][33];
  int t = blockIdx.x;
  const float* W; unsigned short* WT; int K, N, n0, k0, glu = 0;
  if (t < 1728) {
    int rg = t / 576, tt = t - rg * 576;
    W = (rg == 0) ? Wq : (rg == 1) ? Wk : Wv;
    WT = wqkvT + (size_t)rg * 768 * 768;
    K = 768; N = 768; n0 = (tt % 24) * 32; k0 = (tt / 24) * 32;
  } else if (t < 2304) {
    int tt = t - 1728; W = Wo; WT = woT;
    K = 768; N = 768; n0 = (tt % 24) * 32; k0 = (tt / 24) * 32;
  } else if (t < 5376) {
    int tt = t - 2304; W = Win; WT = winT;
    K = 768; N = 4096; n0 = (tt % 128) * 32; k0 = (tt / 128) * 32; glu = 1;
  } else {
    int tt = t - 5376; W = Wout; WT = woutT;
    K = 2048; N = 768; n0 = (tt % 24) * 32; k0 = (tt / 24) * 32;
  }
  int c = threadIdx.x & 31, r8 = threadIdx.x >> 5;
  int col = n0 + c;
  int scol = col;
  if (glu) {
    int b = col >> 5, rr2 = col & 31;
    scol = (rr2 < 16) ? (b * 16 + rr2) : (2048 + b * 16 + rr2 - 16);
  }
  for (int rr = r8; rr < 32; rr += 8)
    tle[rr][c] = W[(size_t)(k0 + rr) * N + scol];
  __syncthreads();
  for (int rn = r8; rn < 32; rn += 8)
    WT[(size_t)(n0 + rn) * K + k0 + c] = f2bf(tle[c][rn]);
}

// ---------------- bf16 MFMA GEMM: 256x256 tile, BK=64, 8-wave, 8-phase pipeline ----------------
// A: MxK bf16 row-major. BT: NxK bf16 row-major. M,N % 256 == 0, K % 128 == 0.
// Double-buffered XOR-swizzled LDS (128 KB); per K-tile-pair iteration: 8 phases,
// each {ds_read subtile || stage 1 half-tile || barrier; lgkm0; 16 MFMA; barrier}.
// vmcnt(2) published via barrier at phases 4/8 (vmcnt(0) in last iter ph4 - tail
// stages are skipped so the counted wait loses its guarantee).
// Stage stream (iter it computes kt c0=2it ph1-4, c1=2it+1 ph5-8):
//   ph1: c1.A1  ph2: c1.B0  ph3: c1.B1  ph4: (c0+2).A0
//   ph5: (c0+2).A1  ph6: (c0+2).B0  ph7: (c0+2).B1  ph8: (c1+2).A0
// Safety: A-half freed after its waves' phase-3 reads, B-half after phase 4;
// every stage issues after the barrier following its region's last read.
// MODE 0: Cf = A@B (+bias) | 1: Cf += | 2: Hg = bf16 | 3: glu-interleaved a*gelu(g)
template<int MODE>
__global__ __launch_bounds__(512, 2) void gemm_bf16(
    const unsigned short* __restrict__ A, const unsigned short* __restrict__ BT,
    float* __restrict__ Cf, unsigned short* __restrict__ Hg,
    const float* __restrict__ bias, int M, int N, int K)
{
  __shared__ unsigned short As[2][256 * 64];
  __shared__ unsigned short Bs[2][256 * 64];
  const int tid = threadIdx.x;
  const int wave = tid >> 6;
  const int lane = tid & 63;
  const int bm = blockIdx.y * 256;
  const int bn = blockIdx.x * 256;
  const int wm = (wave >> 2) * 128;   // 2 M-wave rows
  const int wn = (wave & 3) * 64;     // 4 N-wave cols
  const int fr = lane & 15;
  const int fg = lane >> 4;

  f32x4 acc[8][4];
  #pragma unroll
  for (int i = 0; i < 8; ++i)
    #pragma unroll
    for (int j = 0; j < 4; ++j) acc[i][j] = (f32x4){0.f, 0.f, 0.f, 0.f};

  // staging bases: lane covers row wave*8 + (lane>>3), swizzled src unit (lane&7)^(lane>>3)
  const unsigned short* gA0 = A + (size_t)(bm + wave * 8 + (lane >> 3)) * K
                                + (((lane & 7) ^ (lane >> 3)) << 3);
  const unsigned short* gB0 = BT + (size_t)(bn + wave * 8 + (lane >> 3)) * K
                                 + (((lane & 7) ^ (lane >> 3)) << 3);

#define STAGE_A(KT_, H_) { \
  load_lds16(gA0 + (size_t)(128 * (H_)) * K + (KT_) * 64, \
             &As[(KT_) & 1][(128 * (H_) + wave * 8) * 64]); \
  load_lds16(gA0 + (size_t)(128 * (H_) + 64) * K + (KT_) * 64, \
             &As[(KT_) & 1][(128 * (H_) + 64 + wave * 8) * 64]); }
#define STAGE_B(KT_, H_) { \
  load_lds16(gB0 + (size_t)(128 * (H_)) * K + (KT_) * 64, \
             &Bs[(KT_) & 1][(128 * (H_) + wave * 8) * 64]); \
  load_lds16(gB0 + (size_t)(128 * (H_) + 64) * K + (KT_) * 64, \
             &Bs[(KT_) & 1][(128 * (H_) + 64 + wave * 8) * 64]); }

  short8 a[4][2], b[2][2];

#define LDA_HALF(IB, SL) { \
  _Pragma("unroll") for (int ii = 0; ii < 4; ++ii) { \
    int row_ = wm + 16 * ((IB) + ii) + fr; \
    int rx_ = (row_ & 7) << 3; \
    a[ii][0] = *(const short8*)&As[SL][row_ * 64 + ((fg << 3) ^ rx_)]; \
    a[ii][1] = *(const short8*)&As[SL][row_ * 64 + ((32 + (fg << 3)) ^ rx_)]; } }
#define LDB_PAIR(JB, SL) { \
  _Pragma("unroll") for (int jj = 0; jj < 2; ++jj) { \
    int row_ = wn + 16 * ((JB) + jj) + fr; \
    int rx_ = (row_ & 7) << 3; \
    b[jj][0] = *(const short8*)&Bs[SL][row_ * 64 + ((fg << 3) ^ rx_)]; \
    b[jj][1] = *(const short8*)&Bs[SL][row_ * 64 + ((32 + (fg << 3)) ^ rx_)]; } }
#define MFMA_Q(IB, JB) { \
  _Pragma("unroll") for (int ii = 0; ii < 4; ++ii) \
  _Pragma("unroll") for (int jj = 0; jj < 2; ++jj) { \
    acc[(IB)+ii][(JB)+jj] = __builtin_amdgcn_mfma_f32_16x16x32_bf16( \
        a[ii][0], b[jj][0], acc[(IB)+ii][(JB)+jj], 0, 0, 0); \
    acc[(IB)+ii][(JB)+jj] = __builtin_amdgcn_mfma_f32_16x16x32_bf16( \
        a[ii][1], b[jj][1], acc[(IB)+ii][(JB)+jj], 0, 0, 0); } }
#define PH_MID() \
  __builtin_amdgcn_s_barrier(); \
  asm volatile("s_waitcnt lgkmcnt(0)" ::: "memory"); \
  __builtin_amdgcn_sched_barrier(0); \
  __builtin_amdgcn_s_setprio(1);
#define PH_END() \
  __builtin_amdgcn_s_setprio(0); \
  __builtin_amdgcn_s_barrier();

  const int KT = K >> 6;
  const int ITERS = KT >> 1;

  // prologue: kt0 fully + kt1.A0; publish
  STAGE_A(0, 0); STAGE_A(0, 1); STAGE_B(0, 0); STAGE_B(0, 1); STAGE_A(1, 0);
  asm volatile("s_waitcnt vmcnt(2)" ::: "memory");
  __builtin_amdgcn_s_barrier();

  for (int it = 0; it < ITERS; ++it) {
    const int c1 = 2 * it + 1;
    const int n0 = 2 * it + 2;
    const bool last = (it == ITERS - 1);
    // ---- phase 1: slot0 (i0-3, j0-1) ----
    LDA_HALF(0, 0); LDB_PAIR(0, 0);
    STAGE_A(c1, 1);
    PH_MID(); MFMA_Q(0, 0); PH_END();
    // ---- phase 2: slot0 (i0-3, j2-3) ----
    LDB_PAIR(2, 0);
    STAGE_B(c1, 0);
    PH_MID(); MFMA_Q(0, 2); PH_END();
    // ---- phase 3: slot0 (i4-7, j0-1) ----
    LDA_HALF(4, 0); LDB_PAIR(0, 0);
    STAGE_B(c1, 1);
    PH_MID(); MFMA_Q(4, 0); PH_END();
    // ---- phase 4: slot0 (i4-7, j2-3) + vmcnt checkpoint ----
    LDB_PAIR(2, 0);
    if (n0 < KT) STAGE_A(n0, 0);
    PH_MID(); MFMA_Q(4, 2);
    __builtin_amdgcn_s_setprio(0);
    if (!last) asm volatile("s_waitcnt vmcnt(2)" ::: "memory");
    else       asm volatile("s_waitcnt vmcnt(0)" ::: "memory");
    __builtin_amdgcn_s_barrier();
    // ---- phase 5: slot1 (i0-3, j0-1) ----
    LDA_HALF(0, 1); LDB_PAIR(0, 1);
    if (n0 < KT) STAGE_A(n0, 1);
    PH_MID(); MFMA_Q(0, 0); PH_END();
    // ---- phase 6: slot1 (i0-3, j2-3) ----
    LDB_PAIR(2, 1);
    if (n0 < KT) STAGE_B(n0, 0);
    PH_MID(); MFMA_Q(0, 2); PH_END();
    // ---- phase 7: slot1 (i4-7, j0-1) ----
    LDA_HALF(4, 1); LDB_PAIR(0, 1);
    if (n0 < KT) STAGE_B(n0, 1);
    PH_MID(); MFMA_Q(4, 0); PH_END();
    // ---- phase 8: slot1 (i4-7, j2-3) + vmcnt checkpoint ----
    LDB_PAIR(2, 1);
    if (c1 + 2 < KT) STAGE_A(c1 + 2, 0);
    PH_MID(); MFMA_Q(4, 2);
    __builtin_amdgcn_s_setprio(0);
    if (!last) {
      asm volatile("s_waitcnt vmcnt(2)" ::: "memory");
      __builtin_amdgcn_s_barrier();
    }
  }

  // epilogue
  const int crow0 = bm + wm + ((lane >> 4) << 2);
  const int ccol0 = bn + wn + fr;
  float bv[4];
  if (MODE != 3) {
    #pragma unroll
    for (int j = 0; j < 4; ++j) bv[j] = bias ? bias[ccol0 + 16 * j] : 0.0f;
  }
  #pragma unroll
  for (int i = 0; i < 8; ++i) {
    #pragma unroll
    for (int r = 0; r < 4; ++r) {
      int row = crow0 + 16 * i + r;
      if (MODE == 3) {
        #pragma unroll
        for (int pj = 0; pj < 2; ++pj) {
          int b32 = (bn + wn + 32 * pj) >> 5;
          float av = acc[i][2 * pj][r] + bias[b32 * 16 + fr];
          float gv = acc[i][2 * pj + 1][r] + bias[2048 + b32 * 16 + fr];
          Hg[(size_t)row * (N >> 1) + b32 * 16 + fr] = f2bf(av * geluf_(gv));
        }
      } else {
        #pragma unroll
        for (int j = 0; j < 4; ++j) {
          int col = ccol0 + 16 * j;
          size_t idx = (size_t)row * N + col;
          float val = acc[i][j][r] + bv[j];
          if (MODE == 0) Cf[idx] = val;
          else if (MODE == 1) Cf[idx] += val;
          else Hg[idx] = f2bf(val);
        }
      }
    }
  }
#undef STAGE_A
#undef STAGE_B
#undef LDA_HALF
#undef LDB_PAIR
#undef MFMA_Q
#undef PH_MID
#undef PH_END
}

// ---------------- N=12 dual projection + sigmoid (mix & gate in one pass) ----------------
__global__ __launch_bounds__(256) void proj12x2_kernel(
    const unsigned short* __restrict__ A, const float* __restrict__ Bw1,
    const float* __restrict__ b1, const float* __restrict__ Bw2,
    float* __restrict__ out1, float* __restrict__ out2)
{
  int row = blockIdx.x * 4 + (threadIdx.x >> 6);
  int lane = threadIdx.x & 63;
  const unsigned short* ar = A + (size_t)row * DIM;
  float acc1[HEADS], acc2[HEADS];
  #pragma unroll
  for (int j = 0; j < HEADS; ++j) { acc1[j] = 0.0f; acc2[j] = 0.0f; }
  for (int k2 = lane; k2 < DIM; k2 += 64) {
    float a = bf2f(ar[k2]);
    const float* bw1 = Bw1 + (size_t)k2 * HEADS;
    const float* bw2 = Bw2 + (size_t)k2 * HEADS;
    #pragma unroll
    for (int j = 0; j < HEADS; ++j) {
      acc1[j] = fmaf(a, bw1[j], acc1[j]);
      acc2[j] = fmaf(a, bw2[j], acc2[j]);
    }
  }
  #pragma unroll
  for (int j = 0; j < HEADS; ++j) {
    #pragma unroll
    for (int off = 32; off; off >>= 1) {
      acc1[j] += __shfl_xor(acc1[j], off);
      acc2[j] += __shfl_xor(acc2[j], off);
    }
  }
  if (lane < HEADS) {
    out1[(size_t)row * HEADS + lane] = sigmoidf_(acc1[lane] + b1[lane]);
    out2[(size_t)row * HEADS + lane] = sigmoidf_(acc2[lane]);
  }
}

// ---------------- qkv postprocess (time layers only): v-lerp, k-norm+gamma, rotary ----------------
__global__ __launch_bounds__(768) void qkv_fix_kernel(
    unsigned short* __restrict__ qkv, const unsigned short* __restrict__ rvb,
    const float* __restrict__ mix, const float* __restrict__ kgam, int is_time)
{
  int tok = blockIdx.x;
  int h = threadIdx.x >> 6;
  int d = threadIdx.x & 63;
  size_t rowb = (size_t)tok * LDQ + h * DH + d;
  float kv = bf2f(qkv[rowb + 768]);
  float ss = kv * kv;
  #pragma unroll
  for (int off = 32; off; off >>= 1) ss += __shfl_xor(ss, off);
  float nrm = fmaxf(sqrtf(ss), 1e-12f);
  kv = kv / nrm * (kgam[h * DH + d] + 1.0f) * 8.0f;   // sqrt(DH)=8
  float mv = mix[(size_t)tok * HEADS + h];
  float vv = bf2f(qkv[rowb + 1536]);
  float rvv = bf2f(rvb[(size_t)tok * DIM + h * DH + d]);
  qkv[rowb + 1536] = f2bf(vv + mv * (rvv - vv));
  float qv = bf2f(qkv[rowb]);
  if (is_time) {
    int t = (tok >> 8) & 31;          // token = (b*32+t)*256+s
    int j = d & 31;
    float ang = (float)t * __expf(-(float)j * (9.210340371976184f / 32.0f));
    float cs = cosf(ang), sn = sinf(ang);
    float qp = __shfl_xor(qv, 32);
    float kp = __shfl_xor(kv, 32);
    float sgn = (d < 32) ? -1.0f : 1.0f;
    qv = qv * cs + sgn * qp * sn;
    kv = kv * cs + sgn * kp * sn;
  }
  qkv[rowb] = f2bf(qv);
  qkv[rowb + 768] = f2bf(kv);
}

// ---------------- MFMA space attention, qkv-fix fused into staging ----------------
__global__ __launch_bounds__(256, 2) void attn_mfma_kernel(
    const unsigned short* __restrict__ q, const unsigned short* __restrict__ k,
    const unsigned short* __restrict__ v, const unsigned short* __restrict__ rvb,
    const float* __restrict__ mix, const float* __restrict__ gate,
    const float* __restrict__ kgam, unsigned short* __restrict__ o)
{
  __shared__ __align__(16) unsigned short Ks[128 * 64];    // 16 KB, u^=row&7
  __shared__ __align__(16) unsigned short VsT[64 * 128];   // 16 KB, u^=d&15
  __shared__ __align__(16) unsigned short Pw[4][32 * 64];  // 16 KB, u^=row&7
  const int tid = threadIdx.x;
  const int wave = tid >> 6;
  const int lane = tid & 63;
  const int g = lane >> 4;
  const int c16 = lane & 15;
  const int bp = blockIdx.x >> 1;
  const int qh = blockIdx.x & 1;
  const int h = blockIdx.y;
  const size_t qoff = (size_t)bp * SS * LDQ + h * DH;
  const int qbase = qh * 128 + wave * 32;

  short8 aq[2][2];
  #pragma unroll
  for (int i = 0; i < 2; ++i) {
    const unsigned short* qp = q + qoff + (size_t)(qbase + i * 16 + c16) * LDQ;
    #pragma unroll
    for (int cc = 0; cc < 2; ++cc)
      aq[i][cc] = *(const short8*)(qp + cc * 32 + g * 8);
  }

  f32x4 oacc[2][4];
  float rs[2][4];
  #pragma unroll
  for (int i = 0; i < 2; ++i)
    #pragma unroll
    for (int j = 0; j < 4; ++j) {
      oacc[i][j] = (f32x4){0.f, 0.f, 0.f, 0.f};
      rs[i][j] = 0.f;
    }

  for (int half = 0; half < 2; ++half) {
    const int r0 = half * 128;
    #pragma unroll
    for (int it = 0; it < 4; ++it) {
      int f = tid + it * 256;
      int row = f >> 3, u = f & 7;
      short8 t8 = *(const short8*)(k + qoff + (size_t)(r0 + row) * LDQ + u * 8);
      float kv[8];
      float ss = 0.f;
      #pragma unroll
      for (int c = 0; c < 8; ++c) { kv[c] = bf2f((unsigned short)t8[c]); ss += kv[c] * kv[c]; }
      ss += __shfl_xor(ss, 1); ss += __shfl_xor(ss, 2); ss += __shfl_xor(ss, 4);
      float inv = 8.0f / fmaxf(sqrtf(ss), 1e-12f);   // sqrt(DH)=8 folded in
      float4 kg0 = *(const float4*)(kgam + h * DH + u * 8);
      float4 kg1 = *(const float4*)(kgam + h * DH + u * 8 + 4);
      short8 o8;
      o8[0] = (short)f2bf(kv[0] * inv * (kg0.x + 1.0f));
      o8[1] = (short)f2bf(kv[1] * inv * (kg0.y + 1.0f));
      o8[2] = (short)f2bf(kv[2] * inv * (kg0.z + 1.0f));
      o8[3] = (short)f2bf(kv[3] * inv * (kg0.w + 1.0f));
      o8[4] = (short)f2bf(kv[4] * inv * (kg1.x + 1.0f));
      o8[5] = (short)f2bf(kv[5] * inv * (kg1.y + 1.0f));
      o8[6] = (short)f2bf(kv[6] * inv * (kg1.z + 1.0f));
      o8[7] = (short)f2bf(kv[7] * inv * (kg1.w + 1.0f));
      *(short8*)&Ks[row * 64 + ((u ^ (row & 7)) << 3)] = o8;
    }
    #pragma unroll
    for (int it = 0; it < 4; ++it) {
      int f = tid + it * 256;
      int j = f & 127, dq = f >> 7;
      int tok = bp * SS + r0 + j;
      short8 v8 = *(const short8*)(v + qoff + (size_t)(r0 + j) * LDQ + dq * 8);
      short8 r8 = *(const short8*)(rvb + (size_t)tok * DIM + h * DH + dq * 8);
      float mv = mix[(size_t)tok * HEADS + h];
      int u = j >> 3;
      #pragma unroll
      for (int c = 0; c < 8; ++c) {
        int d = dq * 8 + c;
        float vv = bf2f((unsigned short)v8[c]);
        float val = vv + mv * (bf2f((unsigned short)r8[c]) - vv);
        VsT[d * 128 + ((u ^ (d & 15)) << 3) + (j & 7)] = f2bf(val);
      }
    }
    __syncthreads();

    #pragma unroll
    for (int jc = 0; jc < 2; ++jc) {
      const int lr0 = jc * 64;
      #pragma unroll
      for (int jh = 0; jh < 2; ++jh) {
        f32x4 s[2][2];
        #pragma unroll
        for (int i = 0; i < 2; ++i)
          #pragma unroll
          for (int j = 0; j < 2; ++j) s[i][j] = (f32x4){0.f, 0.f, 0.f, 0.f};
        #pragma unroll
        for (int j2 = 0; j2 < 2; ++j2) {
          int jt = jh * 2 + j2;
          int row = lr0 + jt * 16 + c16;
          short8 b0 = *(const short8*)&Ks[row * 64 + ((g ^ (row & 7)) << 3)];
          short8 b1 = *(const short8*)&Ks[row * 64 + (((4 + g) ^ (row & 7)) << 3)];
          #pragma unroll
          for (int i = 0; i < 2; ++i) {
            s[i][j2] = __builtin_amdgcn_mfma_f32_16x16x32_bf16(aq[i][0], b0, s[i][j2], 0, 0, 0);
            s[i][j2] = __builtin_amdgcn_mfma_f32_16x16x32_bf16(aq[i][1], b1, s[i][j2], 0, 0, 0);
          }
        }
        #pragma unroll
        for (int i = 0; i < 2; ++i) {
          #pragma unroll
          for (int j2 = 0; j2 < 2; ++j2) {
            int pj = (jh * 2 + j2) * 16 + c16;
            int uj = pj >> 3;
            #pragma unroll
            for (int r = 0; r < 4; ++r) {
              float p = softclamp_exp(s[i][j2][r] * 0.125f);
              unsigned short pb = f2bf(p);
              rs[i][r] += bf2f(pb);
              int prow = i * 16 + g * 4 + r;
              Pw[wave][prow * 64 + ((uj ^ (prow & 7)) << 3) + (pj & 7)] = pb;
            }
          }
        }
      }
      #pragma unroll
      for (int jj = 0; jj < 2; ++jj) {
        short8 pa[2];
        #pragma unroll
        for (int i = 0; i < 2; ++i) {
          int prow = i * 16 + c16;
          int u = jj * 4 + g;
          pa[i] = *(const short8*)&Pw[wave][prow * 64 + ((u ^ (prow & 7)) << 3)];
        }
        const int jl = lr0 + jj * 32 + g * 8;
        const int uv = jl >> 3;
        #pragma unroll
        for (int dt = 0; dt < 4; ++dt) {
          int d = dt * 16 + c16;
          short8 bv = *(const short8*)&VsT[d * 128 + ((uv ^ (d & 15)) << 3)];
          #pragma unroll
          for (int i = 0; i < 2; ++i)
            oacc[i][dt] = __builtin_amdgcn_mfma_f32_16x16x32_bf16(pa[i], bv, oacc[i][dt], 0, 0, 0);
        }
      }
    }
    __syncthreads();
  }

  #pragma unroll
  for (int i = 0; i < 2; ++i)
    #pragma unroll
    for (int r = 0; r < 4; ++r) {
      float t = rs[i][r];
      t += __shfl_xor(t, 1); t += __shfl_xor(t, 2);
      t += __shfl_xor(t, 4); t += __shfl_xor(t, 8);
      rs[i][r] = t;
    }
  #pragma unroll
  for (int i = 0; i < 2; ++i) {
    #pragma unroll
    for (int r = 0; r < 4; ++r) {
      int row = qbase + i * 16 + g * 4 + r;
      int tq = bp * SS + row;
      float gt = gate[(size_t)tq * HEADS + h] / rs[i][r];
      unsigned short* op = o + (size_t)tq * DIM + h * DH;
      #pragma unroll
      for (int dt = 0; dt < 4; ++dt)
        op[dt * 16 + c16] = f2bf(oacc[i][dt][r] * gt);
    }
  }
}

// ---------------- MFMA time attention (bf16 in): wave = one (b,s) sequence ----------------
__global__ __launch_bounds__(256, 2) void attn_time_mfma(
    const unsigned short* __restrict__ q, const unsigned short* __restrict__ k,
    const unsigned short* __restrict__ v, const float* __restrict__ gate,
    unsigned short* __restrict__ o)
{
  __shared__ __align__(16) unsigned short VT[4][64 * 32];  // [d][t'], u^=d&3
  __shared__ __align__(16) unsigned short Pw[4][32 * 32];  // [t][t'], u^=t&3
  const int tid = threadIdx.x;
  const int wave = tid >> 6;
  const int lane = tid & 63;
  const int g = lane >> 4;
  const int c16 = lane & 15;
  const int h = blockIdx.y;
  const int sp = blockIdx.x * 4 + wave;                 // 0..511
  const int base = (sp >> 8) * (TT * SS) + (sp & 255);  // b*8192 + s

  short8 aq[2][2], bk[2][2];
  #pragma unroll
  for (int i = 0; i < 2; ++i) {
    const unsigned short* qp = q + (size_t)(base + (i * 16 + c16) * SS) * LDQ + h * DH;
    const unsigned short* kp = k + (size_t)(base + (i * 16 + c16) * SS) * LDQ + h * DH;
    #pragma unroll
    for (int cc = 0; cc < 2; ++cc) {
      aq[i][cc] = *(const short8*)(qp + cc * 32 + g * 8);
      bk[i][cc] = *(const short8*)(kp + cc * 32 + g * 8);
    }
  }

  {
    int tp = lane >> 1;
    int dh0 = (lane & 1) * 32;
    const unsigned short* vp = v + (size_t)(base + tp * SS) * LDQ + h * DH + dh0;
    int ut = tp >> 3;
    #pragma unroll
    for (int j4 = 0; j4 < 4; ++j4) {
      short8 t = *(const short8*)(vp + j4 * 8);
      #pragma unroll
      for (int c = 0; c < 8; ++c) {
        int d = dh0 + j4 * 8 + c;
        VT[wave][d * 32 + ((ut ^ (d & 3)) << 3) + (tp & 7)] = (unsigned short)t[c];
      }
    }
  }

  f32x4 s[2][2];
  #pragma unroll
  for (int i = 0; i < 2; ++i)
    #pragma unroll
    for (int j = 0; j < 2; ++j) s[i][j] = (f32x4){0.f, 0.f, 0.f, 0.f};
  #pragma unroll
  for (int jt = 0; jt < 2; ++jt)
    #pragma unroll
    for (int i = 0; i < 2; ++i) {
      s[i][jt] = __builtin_amdgcn_mfma_f32_16x16x32_bf16(aq[i][0], bk[jt][0], s[i][jt], 0, 0, 0);
      s[i][jt] = __builtin_amdgcn_mfma_f32_16x16x32_bf16(aq[i][1], bk[jt][1], s[i][jt], 0, 0, 0);
    }

  float rs[2][4];
  #pragma unroll
  for (int i = 0; i < 2; ++i)
    #pragma unroll
    for (int r = 0; r < 4; ++r) rs[i][r] = 0.f;
  #pragma unroll
  for (int i = 0; i < 2; ++i) {
    #pragma unroll
    for (int jt = 0; jt < 2; ++jt) {
      int pj = jt * 16 + c16;
      int uj = pj >> 3;
      #pragma unroll
      for (int r = 0; r < 4; ++r) {
        int t = i * 16 + g * 4 + r;
        float p = softclamp_exp(s[i][jt][r] * 0.125f);
        unsigned short pb = (pj <= t) ? f2bf(p) : (unsigned short)0;
        rs[i][r] += bf2f(pb);
        Pw[wave][t * 32 + ((uj ^ (t & 3)) << 3) + (pj & 7)] = pb;
      }
    }
  }

  short8 pa[2];
  #pragma unroll
  for (int i = 0; i < 2; ++i) {
    int prow = i * 16 + c16;
    pa[i] = *(const short8*)&Pw[wave][prow * 32 + ((g ^ (prow & 3)) << 3)];
  }
  f32x4 oacc[2][4];
  #pragma unroll
  for (int dt = 0; dt < 4; ++dt) {
    int d = dt * 16 + c16;
    short8 bv = *(const short8*)&VT[wave][d * 32 + ((g ^ (d & 3)) << 3)];
    #pragma unroll
    for (int i = 0; i < 2; ++i)
      oacc[i][dt] = __builtin_amdgcn_mfma_f32_16x16x32_bf16(
          pa[i], bv, (f32x4){0.f, 0.f, 0.f, 0.f}, 0, 0, 0);
  }

  #pragma unroll
  for (int i = 0; i < 2; ++i)
    #pragma unroll
    for (int r = 0; r < 4; ++r) {
      float t = rs[i][r];
      t += __shfl_xor(t, 1); t += __shfl_xor(t, 2);
      t += __shfl_xor(t, 4); t += __shfl_xor(t, 8);
      rs[i][r] = t;
    }
  #pragma unroll
  for (int i = 0; i < 2; ++i) {
    #pragma unroll
    for (int r = 0; r < 4; ++r) {
      int t = i * 16 + g * 4 + r;
      int tok = base + t * SS;
      float gt = gate[(size_t)tok * HEADS + h] / rs[i][r];
      unsigned short* op = o + (size_t)tok * DIM + h * DH;
      #pragma unroll
      for (int dt = 0; dt < 4; ++dt)
        op[dt * 16 + c16] = f2bf(oacc[i][dt][r] * gt);
    }
  }
}

// ---------------- driver ----------------
extern "C" void kernel_launch(void* const* d_in, const int* in_sizes, int n_in,
                              void* d_out, int out_size, void* d_ws, size_t ws_size,
                              hipStream_t stream)
{
  const float* tokens = (const float*)d_in[0];
  const float* attn_norm_w = (const float*)d_in[1];
  const float* Wq   = (const float*)d_in[2];
  const float* Wk   = (const float*)d_in[3];
  const float* Wv   = (const float*)d_in[4];
  const float* Wo   = (const float*)d_in[5];
  const float* Wg   = (const float*)d_in[6];
  const float* Wmix = (const float*)d_in[7];
  const float* bmix = (const float*)d_in[8];
  const float* kgam = (const float*)d_in[9];
  const float* ffw  = (const float*)d_in[10];
  const float* Win  = (const float*)d_in[11];
  const float* bin  = (const float*)d_in[12];
  const float* Wout = (const float*)d_in[13];
  const float* bout = (const float*)d_in[14];
  const float* vrw  = (const float*)d_in[15];
  const float* vrW  = (const float*)d_in[16];
  const float* fnw  = (const float*)d_in[17];

  const size_t NT = (size_t)NTOK * DIM;   // 12,582,912
  float* ws  = (float*)d_ws;
  float* x   = ws;                        // NT f32
  float* mix = x + NT;                    // NTOK*12
  float* gate = mix + (size_t)NTOK * HEADS;
  unsigned short* tn   = (unsigned short*)(gate + (size_t)NTOK * HEADS); // NT bf16
  unsigned short* qkv  = tn + NT;                        // NTOK*2304 bf16
  unsigned short* rvb  = qkv + (size_t)NTOK * LDQ;       // NT bf16
  unsigned short* wqkvT = rvb + NT;                      // 2304*768
  unsigned short* woT  = wqkvT + (size_t)2304 * 768;     // 768*768
  unsigned short* winT = woT + (size_t)768 * 768;        // 4096*768 (glu-interleaved)
  unsigned short* woutT= winT + (size_t)4096 * 768;      // 768*2048
  unsigned short* vrWT = woutT + (size_t)768 * 2048;     // 768*768
  unsigned short* hg   = qkv;   // FF hidden [NTOK][2048] aliases qkv

  hipMemcpyAsync(x, tokens, NT * sizeof(float), hipMemcpyDeviceToDevice, stream);

  // value residual: rvb = bf16(rmsnorm(tokens, vrw) @ vrW)
  w_to_bt<<<dim3(24, 24), 256, 0, stream>>>(vrW, vrWT, DIM, DIM);
  rmsnorm_kernel<1><<<NTOK, 256, 0, stream>>>(tokens, vrw, tn);
  gemm_bf16<2><<<dim3(3, 64), 512, 0, stream>>>(
      tn, vrWT, nullptr, rvb, nullptr, NTOK, DIM, DIM);

  for (int i = 0; i < DEPTH; ++i) {
    int is_time = ((i + 1) % 4 == 0) ? 1 : 0;
    w_convert_layer<<<6912, 256, 0, stream>>>(
        Wq + (size_t)i * DIM * DIM, Wk + (size_t)i * DIM * DIM,
        Wv + (size_t)i * DIM * DIM, Wo + (size_t)i * DIM * DIM,
        Win + (size_t)i * DIM * 2 * DFF, Wout + (size_t)i * DFF * DIM,
        wqkvT, woT, winT, woutT);

    rmsnorm_kernel<1><<<NTOK, 256, 0, stream>>>(x, attn_norm_w + (size_t)i * DIM, tn);
    // fused qkv projection -> packed bf16 [tok][2304]
    gemm_bf16<2><<<dim3(9, 64), 512, 0, stream>>>(
        tn, wqkvT, nullptr, qkv, nullptr, NTOK, LDQ, DIM);
    proj12x2_kernel<<<NTOK / 4, 256, 0, stream>>>(
        tn, Wmix + (size_t)i * DIM * HEADS, bmix + (size_t)i * HEADS,
        Wg + (size_t)i * DIM * HEADS, mix, gate);
    if (is_time) {
      qkv_fix_kernel<<<dim3(NTOK), 768, 0, stream>>>(
          qkv, rvb, mix, kgam + (size_t)i * HEADS * DH, is_time);
      attn_time_mfma<<<dim3((BB * SS) / 4, HEADS), 256, 0, stream>>>(
          qkv, qkv + 768, qkv + 1536, gate, tn);
    } else {
      attn_mfma_kernel<<<dim3(BB * TT * 2, HEADS), 256, 0, stream>>>(
          qkv, qkv + 768, qkv + 1536, rvb, mix, gate,
          kgam + (size_t)i * HEADS * DH, tn);
    }
    gemm_bf16<1><<<dim3(3, 64), 512, 0, stream>>>(tn, woT, x, nullptr, nullptr, NTOK, DIM, DIM);
    // FF: rmsnorm -> glu-interleaved in-proj (MODE 3) -> out-proj
    rmsnorm_kernel<1><<<NTOK, 256, 0, stream>>>(x, ffw + (size_t)i * DIM, tn);
    gemm_bf16<3><<<dim3(16, 64), 512, 0, stream>>>(
        tn, winT, nullptr, hg, bin + (size_t)i * 2 * DFF, NTOK, 2 * DFF, DIM);
    gemm_bf16<1><<<dim3(3, 64), 512, 0, stream>>>(
        hg, woutT, x, nullptr, bout + (size_t)i * DIM, NTOK, DIM, DFF);
  }
  rmsnorm_kernel<0><<<NTOK, 256, 0, stream>>>(x, fnw, (float*)d_out);
}